// Round 1
// baseline (1912.394 us; speedup 1.0000x reference)
//
#include <hip/hip_runtime.h>
#include <hip/hip_bf16.h>
#include <cstdint>
#include <cstddef>

#define NROIS 1000
#define PD    12544   // 256 * 49
#define FC_N  1024
#define NLOC  324
#define NSC   81
#define NH    405

// ---------------------------------------------------------------------------
// Kernel 1: pyramid ROI-align + 2x2 max pool.
// Block = (roi, cell) pair, lane = channel. Exactly replicates reference:
//   rif = rois * ([H,W,H,W]-1) / (img-1); 14x14 sample grid at (j+0.5)*step;
//   un-clamped floor/ceil bilinear taps (in-bounds by construction, clamp is
//   a no-op safety net); max over 2x2 subsamples.
// ---------------------------------------------------------------------------
__global__ __launch_bounds__(256) void roi_pool_kernel(
    const float* __restrict__ f2, const float* __restrict__ f3,
    const float* __restrict__ f4, const float* __restrict__ f5,
    const float* __restrict__ rois, const int* __restrict__ img_size,
    float* __restrict__ pooled)
{
    const int b    = blockIdx.x;
    const int roi  = b / 49;
    const int cell = b - roi * 49;
    const int ph   = cell / 7;
    const int pw   = cell - ph * 7;
    const int c    = threadIdx.x;

    const float y1 = rois[roi * 4 + 0];
    const float x1 = rois[roi * 4 + 1];
    const float y2 = rois[roi * 4 + 2];
    const float x2 = rois[roi * 4 + 3];

    const float hh = y2 - y1 + 1.0f;
    const float ww = x2 - x1 + 1.0f;
    float lvlf = floorf(logf(sqrtf(hh * ww) / 224.0f) / 0.693147f + 4.0f);
    lvlf = fminf(fmaxf(lvlf, 2.0f), 5.0f);
    const int lvl = (int)lvlf;

    const float* f;
    int H;
    if (lvl == 2)      { f = f2; H = 256; }
    else if (lvl == 3) { f = f3; H = 128; }
    else if (lvl == 4) { f = f4; H = 64;  }
    else               { f = f5; H = 32;  }
    const int W = H;

    const float imh = (float)img_size[0] - 1.0f;
    const float imw = (float)img_size[1] - 1.0f;
    const float r0 = y1 * (float)(H - 1) / imh;
    const float r1 = x1 * (float)(W - 1) / imw;
    const float r2 = y2 * (float)(H - 1) / imh;
    const float r3 = x2 * (float)(W - 1) / imw;
    const float hs  = (r2 - r0) * (1.0f / 14.0f);
    const float wst = (r3 - r1) * (1.0f / 14.0f);

    const float* fch = f + (size_t)c * H * W;
    float m = -INFINITY;
#pragma unroll
    for (int sy = 0; sy < 2; ++sy) {
        const float cy = ((float)(ph * 2 + sy) + 0.5f) * hs + r0;
        const float fy = floorf(cy);
        int   iu  = (int)fy;
        int   idn = (int)ceilf(cy);
        const float ly = cy - fy;
        iu  = min(max(iu, 0),  H - 1);
        idn = min(max(idn, 0), H - 1);
#pragma unroll
        for (int sx = 0; sx < 2; ++sx) {
            const float cx = ((float)(pw * 2 + sx) + 0.5f) * wst + r1;
            const float fx = floorf(cx);
            int   il = (int)fx;
            int   ir = (int)ceilf(cx);
            const float lx = cx - fx;
            il = min(max(il, 0), W - 1);
            ir = min(max(ir, 0), W - 1);

            const float v00 = fch[iu  * W + il];
            const float v01 = fch[iu  * W + ir];
            const float v10 = fch[idn * W + il];
            const float v11 = fch[idn * W + ir];
            const float v = v00 * (1.0f - ly) * (1.0f - lx)
                          + v10 * ly          * (1.0f - lx)
                          + v01 * (1.0f - ly) * lx
                          + v11 * ly          * lx;
            m = fmaxf(m, v);
        }
    }
    pooled[(size_t)roi * PD + c * 49 + cell] = m;
}

// ---------------------------------------------------------------------------
// Kernel 2: fp32 tiled GEMM, C = relu(A @ B + bias).
// A: MxK row-major, B: KxN row-major. BM=BN=64, BK=16, 256 thr, 4x4 microtile.
// As stored transposed [BK][BM+4] (pad keeps 16B alignment: 68*4=272=17*16).
// ---------------------------------------------------------------------------
__global__ __launch_bounds__(256) void gemm_bias_relu_kernel(
    const float* __restrict__ A, const float* __restrict__ B,
    const float* __restrict__ bias, float* __restrict__ C,
    int M, int N, int K)
{
    const int BM = 64, BN = 64, BK = 16;
    __shared__ float As[BK][BM + 4];
    __shared__ float Bs[BK][BN];

    const int t  = threadIdx.x;
    const int tx = t & 15;
    const int ty = t >> 4;
    const int rowBase = blockIdx.y * BM;
    const int colBase = blockIdx.x * BN;

    const int arow = t >> 2;
    const int acol = (t & 3) << 2;
    const int brow = t >> 4;
    const int bcol = (t & 15) << 2;

    float acc[4][4] = {};

    for (int k0 = 0; k0 < K; k0 += BK) {
        float4 av = make_float4(0.f, 0.f, 0.f, 0.f);
        const int gr = rowBase + arow;
        if (gr < M)
            av = *reinterpret_cast<const float4*>(A + (size_t)gr * K + k0 + acol);
        As[acol + 0][arow] = av.x;
        As[acol + 1][arow] = av.y;
        As[acol + 2][arow] = av.z;
        As[acol + 3][arow] = av.w;

        const float4 bv = *reinterpret_cast<const float4*>(
            B + (size_t)(k0 + brow) * N + colBase + bcol);
        *reinterpret_cast<float4*>(&Bs[brow][bcol]) = bv;
        __syncthreads();

#pragma unroll
        for (int kk = 0; kk < BK; ++kk) {
            const float4 a  = *reinterpret_cast<const float4*>(&As[kk][ty * 4]);
            const float4 bb = *reinterpret_cast<const float4*>(&Bs[kk][tx * 4]);
            const float ar[4] = {a.x, a.y, a.z, a.w};
            const float br[4] = {bb.x, bb.y, bb.z, bb.w};
#pragma unroll
            for (int i = 0; i < 4; ++i)
#pragma unroll
                for (int j = 0; j < 4; ++j)
                    acc[i][j] = fmaf(ar[i], br[j], acc[i][j]);
        }
        __syncthreads();
    }

#pragma unroll
    for (int i = 0; i < 4; ++i) {
        const int row = rowBase + ty * 4 + i;
        if (row >= M) continue;
#pragma unroll
        for (int j = 0; j < 4; ++j) {
            const int col = colBase + tx * 4 + j;
            float v = acc[i][j] + bias[col];
            v = fmaxf(v, 0.0f);
            C[(size_t)row * N + col] = v;
        }
    }
}

// ---------------------------------------------------------------------------
// Kernel 3: dual-head GEMM. B is the virtual concat [Wloc | Wsc] (N=405),
// epilogue splits into the two output regions (no relu).
// ---------------------------------------------------------------------------
__global__ __launch_bounds__(256) void heads_kernel(
    const float* __restrict__ A, const float* __restrict__ Wloc,
    const float* __restrict__ Wsc, const float* __restrict__ bloc,
    const float* __restrict__ bsc, float* __restrict__ out0,
    float* __restrict__ out1, int M, int K)
{
    const int BM = 64, BN = 64, BK = 16;
    __shared__ float As[BK][BM + 4];
    __shared__ float Bs[BK][BN];

    const int t  = threadIdx.x;
    const int tx = t & 15;
    const int ty = t >> 4;
    const int rowBase = blockIdx.y * BM;
    const int colBase = blockIdx.x * BN;

    const int arow = t >> 2;
    const int acol = (t & 3) << 2;
    const int brow = t >> 4;
    const int bcol = (t & 15) << 2;

    float acc[4][4] = {};

    for (int k0 = 0; k0 < K; k0 += BK) {
        float4 av = make_float4(0.f, 0.f, 0.f, 0.f);
        const int gr = rowBase + arow;
        if (gr < M)
            av = *reinterpret_cast<const float4*>(A + (size_t)gr * K + k0 + acol);
        As[acol + 0][arow] = av.x;
        As[acol + 1][arow] = av.y;
        As[acol + 2][arow] = av.z;
        As[acol + 3][arow] = av.w;

        const int krow = k0 + brow;
#pragma unroll
        for (int j = 0; j < 4; ++j) {
            const int colj = colBase + bcol + j;
            float v = 0.0f;
            if (colj < NLOC)      v = Wloc[(size_t)krow * NLOC + colj];
            else if (colj < NH)   v = Wsc[(size_t)krow * NSC + (colj - NLOC)];
            Bs[brow][bcol + j] = v;
        }
        __syncthreads();

#pragma unroll
        for (int kk = 0; kk < BK; ++kk) {
            const float4 a  = *reinterpret_cast<const float4*>(&As[kk][ty * 4]);
            const float4 bb = *reinterpret_cast<const float4*>(&Bs[kk][tx * 4]);
            const float ar[4] = {a.x, a.y, a.z, a.w};
            const float br[4] = {bb.x, bb.y, bb.z, bb.w};
#pragma unroll
            for (int i = 0; i < 4; ++i)
#pragma unroll
                for (int j = 0; j < 4; ++j)
                    acc[i][j] = fmaf(ar[i], br[j], acc[i][j]);
        }
        __syncthreads();
    }

#pragma unroll
    for (int i = 0; i < 4; ++i) {
        const int row = rowBase + ty * 4 + i;
        if (row >= M) continue;
#pragma unroll
        for (int j = 0; j < 4; ++j) {
            const int col = colBase + tx * 4 + j;
            if (col < NLOC) {
                out0[(size_t)row * NLOC + col] = acc[i][j] + bloc[col];
            } else if (col < NH) {
                const int cs = col - NLOC;
                out1[(size_t)row * NSC + cs] = acc[i][j] + bsc[cs];
            }
        }
    }
}

// ---------------------------------------------------------------------------
extern "C" void kernel_launch(void* const* d_in, const int* in_sizes, int n_in,
                              void* d_out, int out_size, void* d_ws, size_t ws_size,
                              hipStream_t stream)
{
    const float* f2   = (const float*)d_in[0];
    const float* f3   = (const float*)d_in[1];
    const float* f4   = (const float*)d_in[2];
    const float* f5   = (const float*)d_in[3];
    const float* rois = (const float*)d_in[4];
    const int*   img  = (const int*)d_in[5];
    const float* W1   = (const float*)d_in[6];
    const float* b1   = (const float*)d_in[7];
    const float* W2   = (const float*)d_in[8];
    const float* b2   = (const float*)d_in[9];
    const float* Wloc = (const float*)d_in[10];
    const float* bloc = (const float*)d_in[11];
    const float* Wsc  = (const float*)d_in[12];
    const float* bsc  = (const float*)d_in[13];
    float* out = (float*)d_out;

    float* pooled = (float*)d_ws;                       // 1000*12544 fp32 = 50.2 MB
    float* fc1    = pooled + (size_t)NROIS * PD;        // 1000*1024 fp32
    float* fc2    = fc1    + (size_t)NROIS * FC_N;      // 1000*1024 fp32

    // 1) pyramid ROI align + pool
    roi_pool_kernel<<<NROIS * 49, 256, 0, stream>>>(f2, f3, f4, f5, rois, img, pooled);

    // 2) fc1 = relu(pooled @ W1 + b1)   M=1000, N=1024, K=12544
    gemm_bias_relu_kernel<<<dim3(16, 16), 256, 0, stream>>>(
        pooled, W1, b1, fc1, NROIS, FC_N, PD);

    // 3) fc2 = relu(fc1 @ W2 + b2)      M=1000, N=1024, K=1024
    gemm_bias_relu_kernel<<<dim3(16, 16), 256, 0, stream>>>(
        fc1, W2, b2, fc2, NROIS, FC_N, FC_N);

    // 4) heads: [out0|out1] = fc2 @ [Wloc|Wsc] + [bloc|bsc]   N=405
    heads_kernel<<<dim3(7, 16), 256, 0, stream>>>(
        fc2, Wloc, Wsc, bloc, bsc, out, out + (size_t)NROIS * NLOC, NROIS, FC_N);
}

// Round 2
// 787.237 us; speedup vs baseline: 2.4292x; 2.4292x over previous
//
#include <hip/hip_runtime.h>
#include <hip/hip_bf16.h>
#include <cstdint>
#include <cstddef>

#define NROIS 1000
#define PD    12544   // 256 * 49
#define FC_N  1024
#define NLOC  324
#define NSC   81
#define NH    405
#define SPLITK 4

// float offsets inside d_ws
#define OFF_T2   0u
#define OFF_T3   16777216u           // 256*256*256
#define OFF_T4   20971520u           // + 128*128*256
#define OFF_T5   22020096u           // + 64*64*256
#define OFF_POOL 22282240u           // + 32*32*256  (featsT total)
// aliased into featsT region (featsT dead after roi_pool):
#define OFF_PART 0u                  // SPLITK * 1000*1024 = 4,096,000 floats
#define OFF_FC1  4194304u            // padded start, 1,024,000 floats
#define OFF_FC2  5242880u

// ---------------------------------------------------------------------------
// Transpose one pyramid level [256][P] -> [P][256]. 64x64 LDS tiles.
// ---------------------------------------------------------------------------
__global__ __launch_bounds__(256) void transpose_feat_kernel(
    const float* __restrict__ src, float* __restrict__ dst, int P)
{
    __shared__ float tile[64][65];
    const int p0  = blockIdx.x * 64;
    const int c0  = blockIdx.y * 64;
    const int col = threadIdx.x & 63;
    const int r0  = threadIdx.x >> 6;   // 0..3
#pragma unroll
    for (int r = r0; r < 64; r += 4)
        tile[r][col] = src[(size_t)(c0 + r) * P + p0 + col];
    __syncthreads();
#pragma unroll
    for (int r = r0; r < 64; r += 4)
        dst[(size_t)(p0 + r) * 256 + c0 + col] = tile[col][r];
}

// ---------------------------------------------------------------------------
// ROI align + 2x2 max, reading transposed features [pix][256].
// Block = (roi, cell), lane = channel. Fully coalesced reads and writes.
// pooled layout: [roi][cell*256 + c] (k-permutation folded into GEMM1 B-read).
// ---------------------------------------------------------------------------
__global__ __launch_bounds__(256) void roi_pool_kernel(
    const float* __restrict__ fT, const float* __restrict__ rois,
    const int* __restrict__ img_size, float* __restrict__ pooled)
{
    const int b    = blockIdx.x;
    const int roi  = b / 49;
    const int cell = b - roi * 49;
    const int ph   = cell / 7;
    const int pw   = cell - ph * 7;
    const int c    = threadIdx.x;

    const float y1 = rois[roi * 4 + 0];
    const float x1 = rois[roi * 4 + 1];
    const float y2 = rois[roi * 4 + 2];
    const float x2 = rois[roi * 4 + 3];

    const float hh = y2 - y1 + 1.0f;
    const float ww = x2 - x1 + 1.0f;
    float lvlf = floorf(logf(sqrtf(hh * ww) / 224.0f) / 0.693147f + 4.0f);
    lvlf = fminf(fmaxf(lvlf, 2.0f), 5.0f);
    const int lvl = (int)lvlf;

    const float* f;
    int H;
    if (lvl == 2)      { f = fT + OFF_T2; H = 256; }
    else if (lvl == 3) { f = fT + OFF_T3; H = 128; }
    else if (lvl == 4) { f = fT + OFF_T4; H = 64;  }
    else               { f = fT + OFF_T5; H = 32;  }
    const int W = H;

    const float imh = (float)img_size[0] - 1.0f;
    const float imw = (float)img_size[1] - 1.0f;
    const float r0 = y1 * (float)(H - 1) / imh;
    const float r1 = x1 * (float)(W - 1) / imw;
    const float r2 = y2 * (float)(H - 1) / imh;
    const float r3 = x2 * (float)(W - 1) / imw;
    const float hs  = (r2 - r0) * (1.0f / 14.0f);
    const float wst = (r3 - r1) * (1.0f / 14.0f);

    float m = -INFINITY;
#pragma unroll
    for (int sy = 0; sy < 2; ++sy) {
        const float cy = ((float)(ph * 2 + sy) + 0.5f) * hs + r0;
        const float fy = floorf(cy);
        int   iu  = (int)fy;
        int   idn = (int)ceilf(cy);
        const float ly = cy - fy;
        iu  = min(max(iu, 0),  H - 1);
        idn = min(max(idn, 0), H - 1);
#pragma unroll
        for (int sx = 0; sx < 2; ++sx) {
            const float cx = ((float)(pw * 2 + sx) + 0.5f) * wst + r1;
            const float fx = floorf(cx);
            int   il = (int)fx;
            int   ir = (int)ceilf(cx);
            const float lx = cx - fx;
            il = min(max(il, 0), W - 1);
            ir = min(max(ir, 0), W - 1);

            const float v00 = f[(size_t)(iu  * W + il) * 256 + c];
            const float v01 = f[(size_t)(iu  * W + ir) * 256 + c];
            const float v10 = f[(size_t)(idn * W + il) * 256 + c];
            const float v11 = f[(size_t)(idn * W + ir) * 256 + c];
            const float v = v00 * (1.0f - ly) * (1.0f - lx)
                          + v10 * ly          * (1.0f - lx)
                          + v01 * (1.0f - ly) * lx
                          + v11 * ly          * lx;
            m = fmaxf(m, v);
        }
    }
    pooled[(size_t)roi * PD + cell * 256 + c] = m;
}

// ---------------------------------------------------------------------------
// fp32 split-K GEMM: partial[z][m][n] = A[m, kStart:kStart+kLen] @ B[...]
// BM=BN=64, BK=16, 256 thr, 4x4 microtile. grid=(N/64, ceil(M/64), SPLITK).
// permute!=0: B row for logical k is W1[(k&255)*49 + (k>>8)] (pooled layout).
// ---------------------------------------------------------------------------
__global__ __launch_bounds__(256) void gemm_splitk_kernel(
    const float* __restrict__ A, const float* __restrict__ B,
    float* __restrict__ partial, int M, int N, int K, int kLen, int permute)
{
    const int BM = 64, BN = 64, BK = 16;
    __shared__ float As[BK][BM + 4];
    __shared__ float Bs[BK][BN];

    const int t  = threadIdx.x;
    const int tx = t & 15;
    const int ty = t >> 4;
    const int rowBase = blockIdx.y * BM;
    const int colBase = blockIdx.x * BN;
    const int kStart  = blockIdx.z * kLen;

    const int arow = t >> 2;
    const int acol = (t & 3) << 2;
    const int brow = t >> 4;
    const int bcol = (t & 15) << 2;

    float acc[4][4] = {};

    for (int k0 = kStart; k0 < kStart + kLen; k0 += BK) {
        float4 av = make_float4(0.f, 0.f, 0.f, 0.f);
        const int gr = rowBase + arow;
        if (gr < M)
            av = *reinterpret_cast<const float4*>(A + (size_t)gr * K + k0 + acol);
        As[acol + 0][arow] = av.x;
        As[acol + 1][arow] = av.y;
        As[acol + 2][arow] = av.z;
        As[acol + 3][arow] = av.w;

        int krow = k0 + brow;
        if (permute) krow = (krow & 255) * 49 + (krow >> 8);
        const float4 bv = *reinterpret_cast<const float4*>(
            B + (size_t)krow * N + colBase + bcol);
        *reinterpret_cast<float4*>(&Bs[brow][bcol]) = bv;
        __syncthreads();

#pragma unroll
        for (int kk = 0; kk < BK; ++kk) {
            const float4 a  = *reinterpret_cast<const float4*>(&As[kk][ty * 4]);
            const float4 bb = *reinterpret_cast<const float4*>(&Bs[kk][tx * 4]);
            const float ar[4] = {a.x, a.y, a.z, a.w};
            const float br[4] = {bb.x, bb.y, bb.z, bb.w};
#pragma unroll
            for (int i = 0; i < 4; ++i)
#pragma unroll
                for (int j = 0; j < 4; ++j)
                    acc[i][j] = fmaf(ar[i], br[j], acc[i][j]);
        }
        __syncthreads();
    }

    float* p = partial + (size_t)blockIdx.z * M * N;
#pragma unroll
    for (int i = 0; i < 4; ++i) {
        const int row = rowBase + ty * 4 + i;
        if (row >= M) continue;
#pragma unroll
        for (int j = 0; j < 4; ++j)
            p[(size_t)row * N + colBase + tx * 4 + j] = acc[i][j];
    }
}

// ---------------------------------------------------------------------------
// fc[m][n] = relu(sum_s partial[s][m][n] + bias[n]); float4 over M*N.
// ---------------------------------------------------------------------------
__global__ __launch_bounds__(256) void reduce_bias_relu_kernel(
    const float* __restrict__ partial, const float* __restrict__ bias,
    float* __restrict__ out, int MN, int N)
{
    const int i = blockIdx.x * 256 + threadIdx.x;   // float4 index
    if (i * 4 >= MN) return;
    float4 acc = *reinterpret_cast<const float4*>(partial + (size_t)i * 4);
#pragma unroll
    for (int s = 1; s < SPLITK; ++s) {
        const float4 v = *reinterpret_cast<const float4*>(
            partial + (size_t)s * MN + (size_t)i * 4);
        acc.x += v.x; acc.y += v.y; acc.z += v.z; acc.w += v.w;
    }
    const int col = (i * 4) & (FC_N - 1);
    const float4 bv = *reinterpret_cast<const float4*>(bias + col);
    acc.x = fmaxf(acc.x + bv.x, 0.f);
    acc.y = fmaxf(acc.y + bv.y, 0.f);
    acc.z = fmaxf(acc.z + bv.z, 0.f);
    acc.w = fmaxf(acc.w + bv.w, 0.f);
    *reinterpret_cast<float4*>(out + (size_t)i * 4) = acc;
}

// ---------------------------------------------------------------------------
// Dual-head GEMM (unchanged from round 1).
// ---------------------------------------------------------------------------
__global__ __launch_bounds__(256) void heads_kernel(
    const float* __restrict__ A, const float* __restrict__ Wloc,
    const float* __restrict__ Wsc, const float* __restrict__ bloc,
    const float* __restrict__ bsc, float* __restrict__ out0,
    float* __restrict__ out1, int M, int K)
{
    const int BM = 64, BN = 64, BK = 16;
    __shared__ float As[BK][BM + 4];
    __shared__ float Bs[BK][BN];

    const int t  = threadIdx.x;
    const int tx = t & 15;
    const int ty = t >> 4;
    const int rowBase = blockIdx.y * BM;
    const int colBase = blockIdx.x * BN;

    const int arow = t >> 2;
    const int acol = (t & 3) << 2;
    const int brow = t >> 4;
    const int bcol = (t & 15) << 2;

    float acc[4][4] = {};

    for (int k0 = 0; k0 < K; k0 += BK) {
        float4 av = make_float4(0.f, 0.f, 0.f, 0.f);
        const int gr = rowBase + arow;
        if (gr < M)
            av = *reinterpret_cast<const float4*>(A + (size_t)gr * K + k0 + acol);
        As[acol + 0][arow] = av.x;
        As[acol + 1][arow] = av.y;
        As[acol + 2][arow] = av.z;
        As[acol + 3][arow] = av.w;

        const int krow = k0 + brow;
#pragma unroll
        for (int j = 0; j < 4; ++j) {
            const int colj = colBase + bcol + j;
            float v = 0.0f;
            if (colj < NLOC)      v = Wloc[(size_t)krow * NLOC + colj];
            else if (colj < NH)   v = Wsc[(size_t)krow * NSC + (colj - NLOC)];
            Bs[brow][bcol + j] = v;
        }
        __syncthreads();

#pragma unroll
        for (int kk = 0; kk < BK; ++kk) {
            const float4 a  = *reinterpret_cast<const float4*>(&As[kk][ty * 4]);
            const float4 bb = *reinterpret_cast<const float4*>(&Bs[kk][tx * 4]);
            const float ar[4] = {a.x, a.y, a.z, a.w};
            const float br[4] = {bb.x, bb.y, bb.z, bb.w};
#pragma unroll
            for (int i = 0; i < 4; ++i)
#pragma unroll
                for (int j = 0; j < 4; ++j)
                    acc[i][j] = fmaf(ar[i], br[j], acc[i][j]);
        }
        __syncthreads();
    }

#pragma unroll
    for (int i = 0; i < 4; ++i) {
        const int row = rowBase + ty * 4 + i;
        if (row >= M) continue;
#pragma unroll
        for (int j = 0; j < 4; ++j) {
            const int col = colBase + tx * 4 + j;
            if (col < NLOC) {
                out0[(size_t)row * NLOC + col] = acc[i][j] + bloc[col];
            } else if (col < NH) {
                const int cs = col - NLOC;
                out1[(size_t)row * NSC + cs] = acc[i][j] + bsc[cs];
            }
        }
    }
}

// ---------------------------------------------------------------------------
extern "C" void kernel_launch(void* const* d_in, const int* in_sizes, int n_in,
                              void* d_out, int out_size, void* d_ws, size_t ws_size,
                              hipStream_t stream)
{
    const float* f2   = (const float*)d_in[0];
    const float* f3   = (const float*)d_in[1];
    const float* f4   = (const float*)d_in[2];
    const float* f5   = (const float*)d_in[3];
    const float* rois = (const float*)d_in[4];
    const int*   img  = (const int*)d_in[5];
    const float* W1   = (const float*)d_in[6];
    const float* b1   = (const float*)d_in[7];
    const float* W2   = (const float*)d_in[8];
    const float* b2   = (const float*)d_in[9];
    const float* Wloc = (const float*)d_in[10];
    const float* bloc = (const float*)d_in[11];
    const float* Wsc  = (const float*)d_in[12];
    const float* bsc  = (const float*)d_in[13];
    float* out = (float*)d_out;

    float* ws     = (float*)d_ws;
    float* fT     = ws;                 // 22,282,240 floats (89.1 MB)
    float* pooled = ws + OFF_POOL;      // 12,544,000 floats (50.2 MB)
    float* part   = ws + OFF_PART;      // aliases featsT (dead after roi_pool)
    float* fc1    = ws + OFF_FC1;
    float* fc2    = ws + OFF_FC2;

    // 1) transpose features to [pix][256]
    transpose_feat_kernel<<<dim3(1024, 4), 256, 0, stream>>>(f2, fT + OFF_T2, 65536);
    transpose_feat_kernel<<<dim3(256, 4),  256, 0, stream>>>(f3, fT + OFF_T3, 16384);
    transpose_feat_kernel<<<dim3(64, 4),   256, 0, stream>>>(f4, fT + OFF_T4, 4096);
    transpose_feat_kernel<<<dim3(16, 4),   256, 0, stream>>>(f5, fT + OFF_T5, 1024);

    // 2) ROI align + pool (coalesced), pooled layout [roi][cell*256+c]
    roi_pool_kernel<<<NROIS * 49, 256, 0, stream>>>(fT, rois, img, pooled);

    // 3) fc1 = relu(pooled @ P(W1) + b1): split-K, permuted B rows
    gemm_splitk_kernel<<<dim3(16, 16, SPLITK), 256, 0, stream>>>(
        pooled, W1, part, NROIS, FC_N, PD, PD / SPLITK, 1);
    reduce_bias_relu_kernel<<<(NROIS * FC_N / 4 + 255) / 256, 256, 0, stream>>>(
        part, b1, fc1, NROIS * FC_N, FC_N);

    // 4) fc2 = relu(fc1 @ W2 + b2): split-K
    gemm_splitk_kernel<<<dim3(16, 16, SPLITK), 256, 0, stream>>>(
        fc1, W2, part, NROIS, FC_N, FC_N, FC_N / SPLITK, 0);
    reduce_bias_relu_kernel<<<(NROIS * FC_N / 4 + 255) / 256, 256, 0, stream>>>(
        part, b2, fc2, NROIS * FC_N, FC_N);

    // 5) heads
    heads_kernel<<<dim3(7, 16), 256, 0, stream>>>(
        fc2, Wloc, Wsc, bloc, bsc, out, out + (size_t)NROIS * NLOC, NROIS, FC_N);
}

// Round 3
// 427.564 us; speedup vs baseline: 4.4728x; 1.8412x over previous
//
#include <hip/hip_runtime.h>
#include <hip/hip_bf16.h>
#include <cstdint>
#include <cstddef>

typedef __bf16 bf16x8 __attribute__((ext_vector_type(8)));
typedef float floatx4 __attribute__((ext_vector_type(4)));

#define NROIS 1000
#define PD    12544   // 256*49
#define K2_1  25088   // 2*PD  (hi/lo interleaved)
#define FC_N  1024
#define K2_2  2048    // 2*1024
#define NLOC  324
#define NSC   81
#define NH    405
#define SPLITK 8

// ---- workspace layout (float offsets) -------------------------------------
#define OFF_FT   0u          // fT: 22,282,240 floats (89.1 MB), dead after roi_pool
#define OFF_W1T  0u          // aliases fT: 1024*25088 bf16 = 12,845,056 floats
#define OFF_PART 12845056u   // 8*1024*1024 fp32 = 8,388,608 floats (fits in fT region)
#define OFF_T2   0u
#define OFF_T3   16777216u
#define OFF_T4   20971520u
#define OFF_T5   22020096u
#define OFF_POOL 22282240u   // pooled_hl: 1024*25088 bf16 = 12,845,056 floats
#define OFF_W2T  35127296u   // 1024*2048 bf16 = 1,048,576 floats
#define OFF_WHT  36175872u   // 512*2048 bf16  =   524,288 floats
#define OFF_FC1  36700160u   // 1024*2048 bf16 = 1,048,576 floats
#define OFF_FC2  37748736u   // same; end = 38,797,312 floats (155.2 MB)

// ---- bf16 hi/lo helpers ----------------------------------------------------
__device__ __forceinline__ unsigned short f2bf(float x) {
    unsigned int u = __float_as_uint(x);
    u = u + 0x7fffu + ((u >> 16) & 1u);          // RNE
    return (unsigned short)(u >> 16);
}
__device__ __forceinline__ float bf2f(unsigned short h) {
    return __uint_as_float(((unsigned int)h) << 16);
}
__device__ __forceinline__ ushort2 split_hl(float f) {
    const unsigned short hi = f2bf(f);
    const unsigned short lo = f2bf(f - bf2f(hi));
    return make_ushort2(hi, lo);
}

// ---------------------------------------------------------------------------
// Transpose one pyramid level [256][P] -> [P][256] fp32. 64x64 LDS tiles.
// ---------------------------------------------------------------------------
__global__ __launch_bounds__(256) void transpose_feat_kernel(
    const float* __restrict__ src, float* __restrict__ dst, int P)
{
    __shared__ float tile[64][65];
    const int p0  = blockIdx.x * 64;
    const int c0  = blockIdx.y * 64;
    const int col = threadIdx.x & 63;
    const int r0  = threadIdx.x >> 6;
#pragma unroll
    for (int r = r0; r < 64; r += 4)
        tile[r][col] = src[(size_t)(c0 + r) * P + p0 + col];
    __syncthreads();
#pragma unroll
    for (int r = r0; r < 64; r += 4)
        dst[(size_t)(p0 + r) * 256 + c0 + col] = tile[col][r];
}

// ---------------------------------------------------------------------------
// ROI align + 2x2 max over transposed features [pix][256].
// Output: interleaved hi/lo bf16, A-row layout [roi][2*(cell*256+c)].
// ---------------------------------------------------------------------------
__global__ __launch_bounds__(256) void roi_pool_kernel(
    const float* __restrict__ fT, const float* __restrict__ rois,
    const int* __restrict__ img_size, ushort2* __restrict__ pooledHL)
{
    const int b    = blockIdx.x;
    const int roi  = b / 49;
    const int cell = b - roi * 49;
    const int ph   = cell / 7;
    const int pw   = cell - ph * 7;
    const int c    = threadIdx.x;

    const float y1 = rois[roi * 4 + 0];
    const float x1 = rois[roi * 4 + 1];
    const float y2 = rois[roi * 4 + 2];
    const float x2 = rois[roi * 4 + 3];

    const float hh = y2 - y1 + 1.0f;
    const float ww = x2 - x1 + 1.0f;
    float lvlf = floorf(logf(sqrtf(hh * ww) / 224.0f) / 0.693147f + 4.0f);
    lvlf = fminf(fmaxf(lvlf, 2.0f), 5.0f);
    const int lvl = (int)lvlf;

    const float* f;
    int H;
    if (lvl == 2)      { f = fT + OFF_T2; H = 256; }
    else if (lvl == 3) { f = fT + OFF_T3; H = 128; }
    else if (lvl == 4) { f = fT + OFF_T4; H = 64;  }
    else               { f = fT + OFF_T5; H = 32;  }
    const int W = H;

    const float imh = (float)img_size[0] - 1.0f;
    const float imw = (float)img_size[1] - 1.0f;
    const float r0 = y1 * (float)(H - 1) / imh;
    const float r1 = x1 * (float)(W - 1) / imw;
    const float r2 = y2 * (float)(H - 1) / imh;
    const float r3 = x2 * (float)(W - 1) / imw;
    const float hs  = (r2 - r0) * (1.0f / 14.0f);
    const float wst = (r3 - r1) * (1.0f / 14.0f);

    float m = -INFINITY;
#pragma unroll
    for (int sy = 0; sy < 2; ++sy) {
        const float cy = ((float)(ph * 2 + sy) + 0.5f) * hs + r0;
        const float fy = floorf(cy);
        int   iu  = (int)fy;
        int   idn = (int)ceilf(cy);
        const float ly = cy - fy;
        iu  = min(max(iu, 0),  H - 1);
        idn = min(max(idn, 0), H - 1);
#pragma unroll
        for (int sx = 0; sx < 2; ++sx) {
            const float cx = ((float)(pw * 2 + sx) + 0.5f) * wst + r1;
            const float fx = floorf(cx);
            int   il = (int)fx;
            int   ir = (int)ceilf(cx);
            const float lx = cx - fx;
            il = min(max(il, 0), W - 1);
            ir = min(max(ir, 0), W - 1);

            const float v00 = f[(size_t)(iu  * W + il) * 256 + c];
            const float v01 = f[(size_t)(iu  * W + ir) * 256 + c];
            const float v10 = f[(size_t)(idn * W + il) * 256 + c];
            const float v11 = f[(size_t)(idn * W + ir) * 256 + c];
            const float v = v00 * (1.0f - ly) * (1.0f - lx)
                          + v10 * ly          * (1.0f - lx)
                          + v01 * (1.0f - ly) * lx
                          + v11 * ly          * lx;
            m = fmaxf(m, v);
        }
    }
    pooledHL[(size_t)roi * PD + cell * 256 + c] = split_hl(m);
}

// ---------------------------------------------------------------------------
// W1 [12544][1024] fp32 -> W1T [1024 rows][25088] bf16 (transposed, hi/lo
// interleaved along K, GEMM1 k-permutation folded: dest pair p=cell*256+c
// sources row k=c*49+cell).
// ---------------------------------------------------------------------------
__global__ __launch_bounds__(256) void convert_w1_kernel(
    const float* __restrict__ W1, ushort2* __restrict__ W1T)
{
    __shared__ float tile[64][65];
    const int p0  = blockIdx.x * 64;
    const int n0  = blockIdx.y * 64;
    const int col = threadIdx.x & 63;
    const int r0  = threadIdx.x >> 6;
#pragma unroll
    for (int r = r0; r < 64; r += 4) {
        const int pp   = p0 + r;
        const int ksrc = (pp & 255) * 49 + (pp >> 8);
        tile[r][col] = W1[(size_t)ksrc * 1024 + n0 + col];
    }
    __syncthreads();
#pragma unroll
    for (int nr = r0; nr < 64; nr += 4)
        W1T[(size_t)(n0 + nr) * PD + p0 + col] = split_hl(tile[col][nr]);
}

// W2 [1024][1024] -> W2T [1024][2048] bf16 (transposed, hi/lo interleaved)
__global__ __launch_bounds__(256) void convert_w2_kernel(
    const float* __restrict__ W2, ushort2* __restrict__ W2T)
{
    __shared__ float tile[64][65];
    const int p0  = blockIdx.x * 64;
    const int n0  = blockIdx.y * 64;
    const int col = threadIdx.x & 63;
    const int r0  = threadIdx.x >> 6;
#pragma unroll
    for (int r = r0; r < 64; r += 4)
        tile[r][col] = W2[(size_t)(p0 + r) * 1024 + n0 + col];
    __syncthreads();
#pragma unroll
    for (int nr = r0; nr < 64; nr += 4)
        W2T[(size_t)(n0 + nr) * 1024 + p0 + col] = split_hl(tile[col][nr]);
}

// [Wloc|Wsc] -> WhT [512 rows][2048] bf16; rows 0..323 Wloc cols, 324..404 Wsc
__global__ __launch_bounds__(256) void convert_heads_kernel(
    const float* __restrict__ Wloc, const float* __restrict__ Wsc,
    ushort2* __restrict__ WhT)
{
    __shared__ float tile[64][65];
    const int p0  = blockIdx.x * 64;
    const int n0  = blockIdx.y * 64;
    const int col = threadIdx.x & 63;
    const int r0  = threadIdx.x >> 6;
#pragma unroll
    for (int r = r0; r < 64; r += 4) {
        const int pp = p0 + r;
        const int n  = n0 + col;
        float v = 0.0f;
        if (n < NLOC)    v = Wloc[(size_t)pp * NLOC + n];
        else if (n < NH) v = Wsc[(size_t)pp * NSC + (n - NLOC)];
        tile[r][col] = v;
    }
    __syncthreads();
#pragma unroll
    for (int nr = r0; nr < 64; nr += 4)
        WhT[(size_t)(n0 + nr) * 1024 + p0 + col] = split_hl(tile[col][nr]);
}

// ---------------------------------------------------------------------------
// bf16 MFMA GEMM, m97-style: 128x128 tile, BK=64, global_load_lds width 16,
// XOR-swizzled LDS chunks (conflict-free ds_read_b128 under the wave-uniform
// LDS-dest constraint). A [Mpad][K2], B [Npad][K2] both row-major bf16.
// partial[z] += A[:, z*kLen : (z+1)*kLen] @ B^T slice.
// ---------------------------------------------------------------------------
__global__ __launch_bounds__(256, 2) void gemm_bf16_kernel(
    const unsigned short* __restrict__ A,
    const unsigned short* __restrict__ B,
    float* __restrict__ partial,
    int K2, int N, int kLen)
{
    __shared__ __align__(16) unsigned short As[128 * 64];
    __shared__ __align__(16) unsigned short Bs[128 * 64];

    const int tid  = threadIdx.x;
    const int lane = tid & 63;
    const int wave = tid >> 6;
    const int m0 = blockIdx.y * 128;
    const int n0 = blockIdx.x * 128;
    const int kStart = blockIdx.z * kLen;

    // staging map: lane -> (row_in_8, chunkStore); source chunk XOR-swizzled
    const int rIn  = lane >> 3;
    const int cSt  = lane & 7;
    const int cSrc = cSt ^ rIn;

    const int wm = wave >> 1, wn = wave & 1;
    const int mrow = lane & 15, quad = lane >> 4;

    floatx4 acc[4][4];
#pragma unroll
    for (int i = 0; i < 4; ++i)
#pragma unroll
        for (int j = 0; j < 4; ++j)
            acc[i][j] = (floatx4){0.f, 0.f, 0.f, 0.f};

    for (int k0 = kStart; k0 < kStart + kLen; k0 += 64) {
#pragma unroll
        for (int q = 0; q < 4; ++q) {
            const int rowBase = wave * 32 + q * 8;
            const unsigned short* ga =
                A + (size_t)(m0 + rowBase + rIn) * K2 + k0 + cSrc * 8;
            const unsigned short* gb =
                B + (size_t)(n0 + rowBase + rIn) * K2 + k0 + cSrc * 8;
            __builtin_amdgcn_global_load_lds(
                (const __attribute__((address_space(1))) void*)ga,
                (__attribute__((address_space(3))) void*)&As[rowBase * 64], 16, 0, 0);
            __builtin_amdgcn_global_load_lds(
                (const __attribute__((address_space(1))) void*)gb,
                (__attribute__((address_space(3))) void*)&Bs[rowBase * 64], 16, 0, 0);
        }
        __syncthreads();

#pragma unroll
        for (int ks = 0; ks < 2; ++ks) {
            bf16x8 aF[4], bF[4];
#pragma unroll
            for (int i = 0; i < 4; ++i) {
                const int ra = wm * 64 + i * 16 + mrow;
                const int ca = ((ks * 4 + quad) ^ (ra & 7)) * 8;
                aF[i] = *reinterpret_cast<const bf16x8*>(&As[ra * 64 + ca]);
                const int rb = wn * 64 + i * 16 + mrow;
                const int cb = ((ks * 4 + quad) ^ (rb & 7)) * 8;
                bF[i] = *reinterpret_cast<const bf16x8*>(&Bs[rb * 64 + cb]);
            }
#pragma unroll
            for (int i = 0; i < 4; ++i)
#pragma unroll
                for (int j = 0; j < 4; ++j)
                    acc[i][j] = __builtin_amdgcn_mfma_f32_16x16x32_bf16(
                        aF[i], bF[j], acc[i][j], 0, 0, 0);
        }
        __syncthreads();
    }

    // C/D layout: col = lane&15, row = quad*4 + reg (m89-verified)
    float* p = partial + (size_t)blockIdx.z * (size_t)(gridDim.y * 128) * N;
#pragma unroll
    for (int i = 0; i < 4; ++i) {
        const int row = m0 + wm * 64 + i * 16 + quad * 4;
#pragma unroll
        for (int j = 0; j < 4; ++j) {
            const int col = n0 + wn * 64 + j * 16 + mrow;
#pragma unroll
            for (int r = 0; r < 4; ++r)
                p[(size_t)(row + r) * N + col] = acc[i][j][r];
        }
    }
}

// ---------------------------------------------------------------------------
// fc = relu(sum_z partial + bias) -> hi/lo bf16 interleaved [m][2n]
// ---------------------------------------------------------------------------
__global__ __launch_bounds__(256) void reduce_fc_kernel(
    const float* __restrict__ partial, const float* __restrict__ bias,
    ushort2* __restrict__ outHL)
{
    const int idx = blockIdx.x * 256 + threadIdx.x;   // < 1000*1024
    const int m = idx >> 10, n = idx & 1023;
    float s = 0.f;
#pragma unroll
    for (int z = 0; z < SPLITK; ++z)
        s += partial[(size_t)z * 1024 * 1024 + (size_t)m * 1024 + n];
    s = fmaxf(s + bias[n], 0.f);
    outHL[(size_t)m * 1024 + n] = split_hl(s);
}

// heads: sum partials [z][1024][512], add bias, split-store to out0/out1
__global__ __launch_bounds__(256) void reduce_heads_kernel(
    const float* __restrict__ partial, const float* __restrict__ bloc,
    const float* __restrict__ bsc, float* __restrict__ out0,
    float* __restrict__ out1)
{
    const int m = blockIdx.x;   // 0..999
    for (int n = threadIdx.x; n < NH; n += 256) {
        float s = 0.f;
#pragma unroll
        for (int z = 0; z < SPLITK; ++z)
            s += partial[(size_t)z * 1024 * 512 + (size_t)m * 512 + n];
        if (n < NLOC) out0[(size_t)m * NLOC + n] = s + bloc[n];
        else          out1[(size_t)m * NSC + (n - NLOC)] = s + bsc[n - NLOC];
    }
}

// ---------------------------------------------------------------------------
extern "C" void kernel_launch(void* const* d_in, const int* in_sizes, int n_in,
                              void* d_out, int out_size, void* d_ws, size_t ws_size,
                              hipStream_t stream)
{
    const float* f2   = (const float*)d_in[0];
    const float* f3   = (const float*)d_in[1];
    const float* f4   = (const float*)d_in[2];
    const float* f5   = (const float*)d_in[3];
    const float* rois = (const float*)d_in[4];
    const int*   img  = (const int*)d_in[5];
    const float* W1   = (const float*)d_in[6];
    const float* b1   = (const float*)d_in[7];
    const float* W2   = (const float*)d_in[8];
    const float* b2   = (const float*)d_in[9];
    const float* Wloc = (const float*)d_in[10];
    const float* bloc = (const float*)d_in[11];
    const float* Wsc  = (const float*)d_in[12];
    const float* bsc  = (const float*)d_in[13];
    float* out = (float*)d_out;

    float* ws = (float*)d_ws;
    float*   fT     = ws + OFF_FT;
    ushort2* pooled = (ushort2*)(ws + OFF_POOL);
    ushort2* w1t    = (ushort2*)(ws + OFF_W1T);     // aliases fT (dead then)
    float*   part   = ws + OFF_PART;                // aliases fT tail
    ushort2* w2t    = (ushort2*)(ws + OFF_W2T);
    ushort2* wht    = (ushort2*)(ws + OFF_WHT);
    ushort2* fc1    = (ushort2*)(ws + OFF_FC1);
    ushort2* fc2    = (ushort2*)(ws + OFF_FC2);

    // 1) feature transpose to [pix][256]
    transpose_feat_kernel<<<dim3(1024, 4), 256, 0, stream>>>(f2, fT + OFF_T2, 65536);
    transpose_feat_kernel<<<dim3(256, 4),  256, 0, stream>>>(f3, fT + OFF_T3, 16384);
    transpose_feat_kernel<<<dim3(64, 4),   256, 0, stream>>>(f4, fT + OFF_T4, 4096);
    transpose_feat_kernel<<<dim3(16, 4),   256, 0, stream>>>(f5, fT + OFF_T5, 1024);

    // 2) ROI pool -> pooled hi/lo bf16 (rows 1000..1023 stay poison: benign,
    //    their partial rows are never stored)
    roi_pool_kernel<<<NROIS * 49, 256, 0, stream>>>(fT, rois, img, pooled);

    // 3) weight conversions (W1T after roi_pool: aliases fT region)
    convert_w1_kernel<<<dim3(196, 16), 256, 0, stream>>>(W1, w1t);
    convert_w2_kernel<<<dim3(16, 16),  256, 0, stream>>>(W2, w2t);
    convert_heads_kernel<<<dim3(16, 7), 256, 0, stream>>>(Wloc, Wsc, wht);

    // 4) fc1 = relu(pooled @ W1 + b1): K2=25088, splitK=8 (512 blocks)
    gemm_bf16_kernel<<<dim3(8, 8, SPLITK), 256, 0, stream>>>(
        (const unsigned short*)pooled, (const unsigned short*)w1t, part,
        K2_1, 1024, K2_1 / SPLITK);
    reduce_fc_kernel<<<4000, 256, 0, stream>>>(part, b1, fc1);

    // 5) fc2 = relu(fc1 @ W2 + b2): K2=2048
    gemm_bf16_kernel<<<dim3(8, 8, SPLITK), 256, 0, stream>>>(
        (const unsigned short*)fc1, (const unsigned short*)w2t, part,
        K2_2, 1024, K2_2 / SPLITK);
    reduce_fc_kernel<<<4000, 256, 0, stream>>>(part, b2, fc2);

    // 6) heads: N=512 (cols 405..511 garbage, never stored)
    gemm_bf16_kernel<<<dim3(4, 8, SPLITK), 256, 0, stream>>>(
        (const unsigned short*)fc2, (const unsigned short*)wht, part,
        K2_2, 512, K2_2 / SPLITK);
    reduce_heads_kernel<<<NROIS, 256, 0, stream>>>(
        part, bloc, bsc, out, out + (size_t)NROIS * NLOC);
}

// Round 4
// 426.025 us; speedup vs baseline: 4.4889x; 1.0036x over previous
//
#include <hip/hip_runtime.h>
#include <hip/hip_bf16.h>
#include <cstdint>
#include <cstddef>

typedef __bf16 bf16x8 __attribute__((ext_vector_type(8)));
typedef float floatx4 __attribute__((ext_vector_type(4)));

#define NROIS 1000
#define PD    12544   // 256*49
#define K2_1  25088   // 2*PD  (hi/lo interleaved)
#define FC_N  1024
#define K2_2  2048    // 2*1024
#define NLOC  324
#define NSC   81
#define NH    405
#define SPLITK 8

// ---- workspace layout (float offsets) -------------------------------------
#define OFF_FT   0u          // fT: 22,282,240 floats (89.1 MB), dead after roi_pool
#define OFF_W1T  0u          // aliases fT: 1024*25088 bf16 = 12,845,056 floats
#define OFF_PART 12845056u   // 8*1024*1024 fp32 = 8,388,608 floats (in fT region)
#define OFF_T2   0u
#define OFF_T3   16777216u
#define OFF_T4   20971520u
#define OFF_T5   22020096u
#define OFF_POOL 22282240u   // pooled_hl: 1024*25088 bf16 = 12,845,056 floats
#define OFF_W2T  35127296u   // 1024*2048 bf16 = 1,048,576 floats
#define OFF_WHT  36175872u   // 512*2048 bf16  =   524,288 floats
#define OFF_FC1  36700160u   // 1024*2048 bf16 = 1,048,576 floats
#define OFF_FC2  37748736u   // 1,048,576 floats
#define OFF_PERM 38797312u   // 1024 ints; end = 38,798,336 floats (155.2 MB)

// ---- bf16 hi/lo helpers ----------------------------------------------------
__device__ __forceinline__ unsigned short f2bf(float x) {
    unsigned int u = __float_as_uint(x);
    u = u + 0x7fffu + ((u >> 16) & 1u);          // RNE
    return (unsigned short)(u >> 16);
}
__device__ __forceinline__ float bf2f(unsigned short h) {
    return __uint_as_float(((unsigned int)h) << 16);
}
__device__ __forceinline__ ushort2 split_hl(float f) {
    const unsigned short hi = f2bf(f);
    const unsigned short lo = f2bf(f - bf2f(hi));
    return make_ushort2(hi, lo);
}

// ---------------------------------------------------------------------------
// ROI spatial sort: key = (lvl-2)<<26 | morton8x8(center/4)<<10 | idx.
// Single block, 1024-wide bitonic in LDS. perf-only (any permutation correct).
// ---------------------------------------------------------------------------
__global__ __launch_bounds__(1024) void sort_rois_kernel(
    const float* __restrict__ rois, int* __restrict__ perm)
{
    __shared__ unsigned int keys[1024];
    const int t = threadIdx.x;
    unsigned int key = 0xFFFFFFFFu;
    if (t < NROIS) {
        const float y1 = rois[t * 4 + 0];
        const float x1 = rois[t * 4 + 1];
        const float y2 = rois[t * 4 + 2];
        const float x2 = rois[t * 4 + 3];
        const float hh = y2 - y1 + 1.0f;
        const float ww = x2 - x1 + 1.0f;
        float lvlf = floorf(logf(sqrtf(hh * ww) / 224.0f) / 0.693147f + 4.0f);
        lvlf = fminf(fmaxf(lvlf, 2.0f), 5.0f);
        const unsigned lvl = (unsigned)((int)lvlf - 2);
        int qy = (int)((y1 + y2) * 0.125f); qy = min(255, max(0, qy));
        int qx = (int)((x1 + x2) * 0.125f); qx = min(255, max(0, qx));
        unsigned mm = 0;
#pragma unroll
        for (int i = 0; i < 8; ++i)
            mm |= (((unsigned)(qy >> i) & 1u) << (2 * i + 1)) |
                  (((unsigned)(qx >> i) & 1u) << (2 * i));
        key = (lvl << 26) | (mm << 10) | (unsigned)t;
    }
    keys[t] = key;
    __syncthreads();
    for (int size = 2; size <= 1024; size <<= 1) {
        for (int stride = size >> 1; stride > 0; stride >>= 1) {
            const int p = t ^ stride;
            if (p > t) {
                const unsigned a = keys[t], b = keys[p];
                const bool asc = ((t & size) == 0);
                if ((a > b) == asc) { keys[t] = b; keys[p] = a; }
            }
            __syncthreads();
        }
    }
    if (t < NROIS) perm[t] = (int)(keys[t] & 1023u);
}

// ---------------------------------------------------------------------------
// Fused transpose of all 4 pyramid levels [256][P] -> [P][256] fp32.
// grid.x = 1024+256+64+16 = 1360 pixel-tiles, grid.y = 4 channel-tiles.
// ---------------------------------------------------------------------------
__global__ __launch_bounds__(256) void transpose_feat_kernel(
    const float* __restrict__ f2, const float* __restrict__ f3,
    const float* __restrict__ f4, const float* __restrict__ f5,
    float* __restrict__ fT)
{
    __shared__ float tile[64][65];
    int bx = blockIdx.x;
    const float* src; float* dst; int P;
    if (bx < 1024)      {            src = f2; dst = fT + OFF_T2; P = 65536; }
    else if (bx < 1280) { bx -= 1024; src = f3; dst = fT + OFF_T3; P = 16384; }
    else if (bx < 1344) { bx -= 1280; src = f4; dst = fT + OFF_T4; P = 4096; }
    else                { bx -= 1344; src = f5; dst = fT + OFF_T5; P = 1024; }

    const int p0  = bx * 64;
    const int c0  = blockIdx.y * 64;
    const int col = threadIdx.x & 63;
    const int r0  = threadIdx.x >> 6;
#pragma unroll
    for (int r = r0; r < 64; r += 4)
        tile[r][col] = src[(size_t)(c0 + r) * P + p0 + col];
    __syncthreads();
#pragma unroll
    for (int r = r0; r < 64; r += 4)
        dst[(size_t)(p0 + r) * 256 + c0 + col] = tile[col][r];
}

// ---------------------------------------------------------------------------
// ROI align + 2x2 max: ONE BLOCK PER ROI (lane=channel), looping the 14x14
// sample grid row-major so taps stay L1-resident (footprint <= ~30 rows x 1KB).
// Blocks pick ROIs via sorted perm with XCD-interleaved mapping
// j=(b%8)*125+b/8, so each XCD (round-robin heuristic) works one spatial
// cluster -> L2-local taps. Output: interleaved hi/lo bf16 [roi][cell*256+c].
// ---------------------------------------------------------------------------
__global__ __launch_bounds__(256) void roi_pool_kernel(
    const float* __restrict__ fT, const float* __restrict__ rois,
    const int* __restrict__ img_size, const int* __restrict__ perm,
    ushort2* __restrict__ pooledHL)
{
    const int b   = blockIdx.x;                  // 0..999
    const int j   = (b & 7) * 125 + (b >> 3);    // cluster-per-XCD mapping
    const int roi = perm[j];
    const int c   = threadIdx.x;

    const float y1 = rois[roi * 4 + 0];
    const float x1 = rois[roi * 4 + 1];
    const float y2 = rois[roi * 4 + 2];
    const float x2 = rois[roi * 4 + 3];

    const float hh = y2 - y1 + 1.0f;
    const float ww = x2 - x1 + 1.0f;
    float lvlf = floorf(logf(sqrtf(hh * ww) / 224.0f) / 0.693147f + 4.0f);
    lvlf = fminf(fmaxf(lvlf, 2.0f), 5.0f);
    const int lvl = (int)lvlf;

    const float* f;
    int H;
    if (lvl == 2)      { f = fT + OFF_T2; H = 256; }
    else if (lvl == 3) { f = fT + OFF_T3; H = 128; }
    else if (lvl == 4) { f = fT + OFF_T4; H = 64;  }
    else               { f = fT + OFF_T5; H = 32;  }
    const int W = H;

    const float imh = (float)img_size[0] - 1.0f;
    const float imw = (float)img_size[1] - 1.0f;
    const float r0 = y1 * (float)(H - 1) / imh;
    const float r1 = x1 * (float)(W - 1) / imw;
    const float r2 = y2 * (float)(H - 1) / imh;
    const float r3 = x2 * (float)(W - 1) / imw;
    const float hs  = (r2 - r0) * (1.0f / 14.0f);
    const float wst = (r3 - r1) * (1.0f / 14.0f);

    ushort2* outRow = pooledHL + (size_t)roi * PD + c;

    for (int ph = 0; ph < 7; ++ph) {
        float m[7];
#pragma unroll
        for (int i = 0; i < 7; ++i) m[i] = -INFINITY;

#pragma unroll
        for (int syy = 0; syy < 2; ++syy) {
            const float cy = ((float)(ph * 2 + syy) + 0.5f) * hs + r0;
            const float fy = floorf(cy);
            int   iu  = (int)fy;
            int   idn = (int)ceilf(cy);
            const float ly = cy - fy;
            iu  = min(max(iu, 0),  H - 1);
            idn = min(max(idn, 0), H - 1);
            const float wU = 1.0f - ly, wD = ly;
            const float* rowU = f + (size_t)(iu  * W) * 256;
            const float* rowD = f + (size_t)(idn * W) * 256;

#pragma unroll
            for (int sx = 0; sx < 14; ++sx) {
                const float cx = ((float)sx + 0.5f) * wst + r1;
                const float fx = floorf(cx);
                int   il = (int)fx;
                int   ir = (int)ceilf(cx);
                const float lx = cx - fx;
                il = min(max(il, 0), W - 1);
                ir = min(max(ir, 0), W - 1);

                const float v00 = rowU[il * 256 + c];
                const float v01 = rowU[ir * 256 + c];
                const float v10 = rowD[il * 256 + c];
                const float v11 = rowD[ir * 256 + c];
                const float v = (v00 * (1.0f - lx) + v01 * lx) * wU
                              + (v10 * (1.0f - lx) + v11 * lx) * wD;
                m[sx >> 1] = fmaxf(m[sx >> 1], v);
            }
        }
#pragma unroll
        for (int pw = 0; pw < 7; ++pw)
            outRow[(ph * 7 + pw) * 256] = split_hl(m[pw]);
    }
}

// ---------------------------------------------------------------------------
// W1 [12544][1024] fp32 -> W1T [1024 rows][25088] bf16 (transposed, hi/lo
// interleaved along K, GEMM1 k-permutation folded: dest pair p=cell*256+c
// sources row k=c*49+cell).
// ---------------------------------------------------------------------------
__global__ __launch_bounds__(256) void convert_w1_kernel(
    const float* __restrict__ W1, ushort2* __restrict__ W1T)
{
    __shared__ float tile[64][65];
    const int p0  = blockIdx.x * 64;
    const int n0  = blockIdx.y * 64;
    const int col = threadIdx.x & 63;
    const int r0  = threadIdx.x >> 6;
#pragma unroll
    for (int r = r0; r < 64; r += 4) {
        const int pp   = p0 + r;
        const int ksrc = (pp & 255) * 49 + (pp >> 8);
        tile[r][col] = W1[(size_t)ksrc * 1024 + n0 + col];
    }
    __syncthreads();
#pragma unroll
    for (int nr = r0; nr < 64; nr += 4)
        W1T[(size_t)(n0 + nr) * PD + p0 + col] = split_hl(tile[col][nr]);
}

// W2 [1024][1024] -> W2T [1024][2048] bf16 (transposed, hi/lo interleaved)
__global__ __launch_bounds__(256) void convert_w2_kernel(
    const float* __restrict__ W2, ushort2* __restrict__ W2T)
{
    __shared__ float tile[64][65];
    const int p0  = blockIdx.x * 64;
    const int n0  = blockIdx.y * 64;
    const int col = threadIdx.x & 63;
    const int r0  = threadIdx.x >> 6;
#pragma unroll
    for (int r = r0; r < 64; r += 4)
        tile[r][col] = W2[(size_t)(p0 + r) * 1024 + n0 + col];
    __syncthreads();
#pragma unroll
    for (int nr = r0; nr < 64; nr += 4)
        W2T[(size_t)(n0 + nr) * 1024 + p0 + col] = split_hl(tile[col][nr]);
}

// [Wloc|Wsc] -> WhT [512 rows][2048] bf16; rows 0..323 Wloc cols, 324..404 Wsc
__global__ __launch_bounds__(256) void convert_heads_kernel(
    const float* __restrict__ Wloc, const float* __restrict__ Wsc,
    ushort2* __restrict__ WhT)
{
    __shared__ float tile[64][65];
    const int p0  = blockIdx.x * 64;
    const int n0  = blockIdx.y * 64;
    const int col = threadIdx.x & 63;
    const int r0  = threadIdx.x >> 6;
#pragma unroll
    for (int r = r0; r < 64; r += 4) {
        const int pp = p0 + r;
        const int n  = n0 + col;
        float v = 0.0f;
        if (n < NLOC)    v = Wloc[(size_t)pp * NLOC + n];
        else if (n < NH) v = Wsc[(size_t)pp * NSC + (n - NLOC)];
        tile[r][col] = v;
    }
    __syncthreads();
#pragma unroll
    for (int nr = r0; nr < 64; nr += 4)
        WhT[(size_t)(n0 + nr) * 1024 + p0 + col] = split_hl(tile[col][nr]);
}

// ---------------------------------------------------------------------------
// bf16 MFMA GEMM, m97-style: 128x128 tile, BK=64, global_load_lds width 16,
// XOR-swizzled LDS chunks. A [Mpad][K2], B [Npad][K2] row-major bf16.
// partial[z] = A[:, z*kLen:(z+1)*kLen] @ B^T slice.
// ---------------------------------------------------------------------------
__global__ __launch_bounds__(256, 2) void gemm_bf16_kernel(
    const unsigned short* __restrict__ A,
    const unsigned short* __restrict__ B,
    float* __restrict__ partial,
    int K2, int N, int kLen)
{
    __shared__ __align__(16) unsigned short As[128 * 64];
    __shared__ __align__(16) unsigned short Bs[128 * 64];

    const int tid  = threadIdx.x;
    const int lane = tid & 63;
    const int wave = tid >> 6;
    const int m0 = blockIdx.y * 128;
    const int n0 = blockIdx.x * 128;
    const int kStart = blockIdx.z * kLen;

    const int rIn  = lane >> 3;
    const int cSt  = lane & 7;
    const int cSrc = cSt ^ rIn;
    (void)cSt;

    const int wm = wave >> 1, wn = wave & 1;
    const int mrow = lane & 15, quad = lane >> 4;

    floatx4 acc[4][4];
#pragma unroll
    for (int i = 0; i < 4; ++i)
#pragma unroll
        for (int j = 0; j < 4; ++j)
            acc[i][j] = (floatx4){0.f, 0.f, 0.f, 0.f};

    for (int k0 = kStart; k0 < kStart + kLen; k0 += 64) {
#pragma unroll
        for (int q = 0; q < 4; ++q) {
            const int rowBase = wave * 32 + q * 8;
            const unsigned short* ga =
                A + (size_t)(m0 + rowBase + rIn) * K2 + k0 + cSrc * 8;
            const unsigned short* gb =
                B + (size_t)(n0 + rowBase + rIn) * K2 + k0 + cSrc * 8;
            __builtin_amdgcn_global_load_lds(
                (const __attribute__((address_space(1))) void*)ga,
                (__attribute__((address_space(3))) void*)&As[rowBase * 64], 16, 0, 0);
            __builtin_amdgcn_global_load_lds(
                (const __attribute__((address_space(1))) void*)gb,
                (__attribute__((address_space(3))) void*)&Bs[rowBase * 64], 16, 0, 0);
        }
        __syncthreads();

#pragma unroll
        for (int ks = 0; ks < 2; ++ks) {
            bf16x8 aF[4], bF[4];
#pragma unroll
            for (int i = 0; i < 4; ++i) {
                const int ra = wm * 64 + i * 16 + mrow;
                const int ca = ((ks * 4 + quad) ^ (ra & 7)) * 8;
                aF[i] = *reinterpret_cast<const bf16x8*>(&As[ra * 64 + ca]);
                const int rb = wn * 64 + i * 16 + mrow;
                const int cb = ((ks * 4 + quad) ^ (rb & 7)) * 8;
                bF[i] = *reinterpret_cast<const bf16x8*>(&Bs[rb * 64 + cb]);
            }
#pragma unroll
            for (int i = 0; i < 4; ++i)
#pragma unroll
                for (int j = 0; j < 4; ++j)
                    acc[i][j] = __builtin_amdgcn_mfma_f32_16x16x32_bf16(
                        aF[i], bF[j], acc[i][j], 0, 0, 0);
        }
        __syncthreads();
    }

    float* p = partial + (size_t)blockIdx.z * (size_t)(gridDim.y * 128) * N;
#pragma unroll
    for (int i = 0; i < 4; ++i) {
        const int row = m0 + wm * 64 + i * 16 + quad * 4;
#pragma unroll
        for (int j = 0; j < 4; ++j) {
            const int col = n0 + wn * 64 + j * 16 + mrow;
#pragma unroll
            for (int r = 0; r < 4; ++r)
                p[(size_t)(row + r) * N + col] = acc[i][j][r];
        }
    }
}

// ---------------------------------------------------------------------------
// fc = relu(sum_z partial + bias) -> hi/lo bf16 interleaved [m][2n]
// ---------------------------------------------------------------------------
__global__ __launch_bounds__(256) void reduce_fc_kernel(
    const float* __restrict__ partial, const float* __restrict__ bias,
    ushort2* __restrict__ outHL)
{
    const int idx = blockIdx.x * 256 + threadIdx.x;   // < 1000*1024
    const int m = idx >> 10, n = idx & 1023;
    float s = 0.f;
#pragma unroll
    for (int z = 0; z < SPLITK; ++z)
        s += partial[(size_t)z * 1024 * 1024 + (size_t)m * 1024 + n];
    s = fmaxf(s + bias[n], 0.f);
    outHL[(size_t)m * 1024 + n] = split_hl(s);
}

// heads: sum partials [z][1024][512], add bias, split-store to out0/out1
__global__ __launch_bounds__(256) void reduce_heads_kernel(
    const float* __restrict__ partial, const float* __restrict__ bloc,
    const float* __restrict__ bsc, float* __restrict__ out0,
    float* __restrict__ out1)
{
    const int m = blockIdx.x;   // 0..999
    for (int n = threadIdx.x; n < NH; n += 256) {
        float s = 0.f;
#pragma unroll
        for (int z = 0; z < SPLITK; ++z)
            s += partial[(size_t)z * 1024 * 512 + (size_t)m * 512 + n];
        if (n < NLOC) out0[(size_t)m * NLOC + n] = s + bloc[n];
        else          out1[(size_t)m * NSC + (n - NLOC)] = s + bsc[n - NLOC];
    }
}

// ---------------------------------------------------------------------------
extern "C" void kernel_launch(void* const* d_in, const int* in_sizes, int n_in,
                              void* d_out, int out_size, void* d_ws, size_t ws_size,
                              hipStream_t stream)
{
    const float* f2   = (const float*)d_in[0];
    const float* f3   = (const float*)d_in[1];
    const float* f4   = (const float*)d_in[2];
    const float* f5   = (const float*)d_in[3];
    const float* rois = (const float*)d_in[4];
    const int*   img  = (const int*)d_in[5];
    const float* W1   = (const float*)d_in[6];
    const float* b1   = (const float*)d_in[7];
    const float* W2   = (const float*)d_in[8];
    const float* b2   = (const float*)d_in[9];
    const float* Wloc = (const float*)d_in[10];
    const float* bloc = (const float*)d_in[11];
    const float* Wsc  = (const float*)d_in[12];
    const float* bsc  = (const float*)d_in[13];
    float* out = (float*)d_out;

    float* ws = (float*)d_ws;
    float*   fT     = ws + OFF_FT;
    ushort2* pooled = (ushort2*)(ws + OFF_POOL);
    ushort2* w1t    = (ushort2*)(ws + OFF_W1T);     // aliases fT (dead then)
    float*   part   = ws + OFF_PART;                // aliases fT tail
    ushort2* w2t    = (ushort2*)(ws + OFF_W2T);
    ushort2* wht    = (ushort2*)(ws + OFF_WHT);
    ushort2* fc1    = (ushort2*)(ws + OFF_FC1);
    ushort2* fc2    = (ushort2*)(ws + OFF_FC2);
    int*     perm   = (int*)(ws + OFF_PERM);

    // 0) spatial ROI sort (perf-only permutation)
    sort_rois_kernel<<<1, 1024, 0, stream>>>(rois, perm);

    // 1) feature transpose to [pix][256], all levels fused
    transpose_feat_kernel<<<dim3(1360, 4), 256, 0, stream>>>(f2, f3, f4, f5, fT);

    // 2) ROI pool, block-per-ROI, sorted+XCD-interleaved
    roi_pool_kernel<<<NROIS, 256, 0, stream>>>(fT, rois, img, perm, pooled);

    // 3) weight conversions (W1T aliases fT region, dead after roi_pool)
    convert_w1_kernel<<<dim3(196, 16), 256, 0, stream>>>(W1, w1t);
    convert_w2_kernel<<<dim3(16, 16),  256, 0, stream>>>(W2, w2t);
    convert_heads_kernel<<<dim3(16, 7), 256, 0, stream>>>(Wloc, Wsc, wht);

    // 4) fc1 = relu(pooled @ W1 + b1): K2=25088, splitK=8 (512 blocks)
    gemm_bf16_kernel<<<dim3(8, 8, SPLITK), 256, 0, stream>>>(
        (const unsigned short*)pooled, (const unsigned short*)w1t, part,
        K2_1, 1024, K2_1 / SPLITK);
    reduce_fc_kernel<<<4000, 256, 0, stream>>>(part, b1, fc1);

    // 5) fc2 = relu(fc1 @ W2 + b2): K2=2048
    gemm_bf16_kernel<<<dim3(8, 8, SPLITK), 256, 0, stream>>>(
        (const unsigned short*)fc1, (const unsigned short*)w2t, part,
        K2_2, 1024, K2_2 / SPLITK);
    reduce_fc_kernel<<<4000, 256, 0, stream>>>(part, b2, fc2);

    // 6) heads: N=512 (cols 405..511 garbage, never stored)
    gemm_bf16_kernel<<<dim3(4, 8, SPLITK), 256, 0, stream>>>(
        (const unsigned short*)fc2, (const unsigned short*)wht, part,
        K2_2, 512, K2_2 / SPLITK);
    reduce_heads_kernel<<<NROIS, 256, 0, stream>>>(
        part, bloc, bsc, out, out + (size_t)NROIS * NLOC);
}

// Round 5
// 393.683 us; speedup vs baseline: 4.8577x; 1.0822x over previous
//
#include <hip/hip_runtime.h>
#include <hip/hip_bf16.h>
#include <cstdint>
#include <cstddef>

typedef __bf16 bf16x8 __attribute__((ext_vector_type(8)));
typedef float floatx4 __attribute__((ext_vector_type(4)));

#define NROIS 1000
#define PD    12544   // 256*49
#define K2_1  25088   // 2*PD  (hi/lo interleaved)
#define FC_N  1024
#define K2_2  2048    // 2*1024
#define NLOC  324
#define NSC   81
#define NH    405

// ---- workspace layout (float offsets) -------------------------------------
#define OFF_FT   0u          // fT: 22,282,240 floats (89.1 MB), dead after roi_pool
#define OFF_W1T  0u          // aliases fT: 1024*25088 bf16 = 12,845,056 floats
#define OFF_PART 12845056u   // 8*1024*1024 fp32 = 8,388,608 floats (in fT region)
#define OFF_T2   0u
#define OFF_T3   16777216u
#define OFF_T4   20971520u
#define OFF_T5   22020096u
#define OFF_POOL 22282240u   // pooled_hl: 1024*25088 bf16 = 12,845,056 floats
#define OFF_W2T  35127296u   // 1024*2048 bf16 = 1,048,576 floats
#define OFF_WHT  36175872u   // 512*2048 bf16  =   524,288 floats
#define OFF_FC1  36700160u   // 1024*2048 bf16 = 1,048,576 floats
#define OFF_FC2  37748736u   // end = 38,797,312 floats (155.2 MB)

// ---- bf16 hi/lo helpers ----------------------------------------------------
__device__ __forceinline__ unsigned short f2bf(float x) {
    unsigned int u = __float_as_uint(x);
    u = u + 0x7fffu + ((u >> 16) & 1u);          // RNE
    return (unsigned short)(u >> 16);
}
__device__ __forceinline__ float bf2f(unsigned short h) {
    return __uint_as_float(((unsigned int)h) << 16);
}
__device__ __forceinline__ ushort2 split_hl(float f) {
    const unsigned short hi = f2bf(f);
    const unsigned short lo = f2bf(f - bf2f(hi));
    return make_ushort2(hi, lo);
}

// ---------------------------------------------------------------------------
// Fused transpose of all 4 pyramid levels [256][P] -> [P][256] fp32.
// grid.x = 1024+256+64+16 = 1360 pixel-tiles, grid.y = 4 channel-tiles.
// ---------------------------------------------------------------------------
__global__ __launch_bounds__(256) void transpose_feat_kernel(
    const float* __restrict__ f2, const float* __restrict__ f3,
    const float* __restrict__ f4, const float* __restrict__ f5,
    float* __restrict__ fT)
{
    __shared__ float tile[64][65];
    int bx = blockIdx.x;
    const float* src; float* dst; int P;
    if (bx < 1024)      {            src = f2; dst = fT + OFF_T2; P = 65536; }
    else if (bx < 1280) { bx -= 1024; src = f3; dst = fT + OFF_T3; P = 16384; }
    else if (bx < 1344) { bx -= 1280; src = f4; dst = fT + OFF_T4; P = 4096; }
    else                { bx -= 1344; src = f5; dst = fT + OFF_T5; P = 1024; }

    const int p0  = bx * 64;
    const int c0  = blockIdx.y * 64;
    const int col = threadIdx.x & 63;
    const int r0  = threadIdx.x >> 6;
#pragma unroll
    for (int r = r0; r < 64; r += 4)
        tile[r][col] = src[(size_t)(c0 + r) * P + p0 + col];
    __syncthreads();
#pragma unroll
    for (int r = r0; r < 64; r += 4)
        dst[(size_t)(p0 + r) * 256 + c0 + col] = tile[col][r];
}

// ---------------------------------------------------------------------------
// ROI align + 2x2 max: one block per (roi, ph) -> grid 7000 for latency
// hiding. lane = channel; 2x14 samples, 4 taps each; writes 7 cells.
// Output: interleaved hi/lo bf16 [roi][cell*256+c].
// ---------------------------------------------------------------------------
__global__ __launch_bounds__(256) void roi_pool_kernel(
    const float* __restrict__ fT, const float* __restrict__ rois,
    const int* __restrict__ img_size, ushort2* __restrict__ pooledHL)
{
    const int roi = blockIdx.x;        // 0..999
    const int ph  = blockIdx.y;        // 0..6
    const int c   = threadIdx.x;

    const float y1 = rois[roi * 4 + 0];
    const float x1 = rois[roi * 4 + 1];
    const float y2 = rois[roi * 4 + 2];
    const float x2 = rois[roi * 4 + 3];

    const float hh = y2 - y1 + 1.0f;
    const float ww = x2 - x1 + 1.0f;
    float lvlf = floorf(logf(sqrtf(hh * ww) / 224.0f) / 0.693147f + 4.0f);
    lvlf = fminf(fmaxf(lvlf, 2.0f), 5.0f);
    const int lvl = (int)lvlf;

    const float* f;
    int H;
    if (lvl == 2)      { f = fT + OFF_T2; H = 256; }
    else if (lvl == 3) { f = fT + OFF_T3; H = 128; }
    else if (lvl == 4) { f = fT + OFF_T4; H = 64;  }
    else               { f = fT + OFF_T5; H = 32;  }
    const int W = H;

    const float imh = (float)img_size[0] - 1.0f;
    const float imw = (float)img_size[1] - 1.0f;
    const float r0 = y1 * (float)(H - 1) / imh;
    const float r1 = x1 * (float)(W - 1) / imw;
    const float r2 = y2 * (float)(H - 1) / imh;
    const float r3 = x2 * (float)(W - 1) / imw;
    const float hs  = (r2 - r0) * (1.0f / 14.0f);
    const float wst = (r3 - r1) * (1.0f / 14.0f);

    float m[7];
#pragma unroll
    for (int i = 0; i < 7; ++i) m[i] = -INFINITY;

#pragma unroll
    for (int syy = 0; syy < 2; ++syy) {
        const float cy = ((float)(ph * 2 + syy) + 0.5f) * hs + r0;
        const float fy = floorf(cy);
        int   iu  = (int)fy;
        int   idn = (int)ceilf(cy);
        const float ly = cy - fy;
        iu  = min(max(iu, 0),  H - 1);
        idn = min(max(idn, 0), H - 1);
        const float wU = 1.0f - ly, wD = ly;
        const float* rowU = f + (size_t)(iu  * W) * 256;
        const float* rowD = f + (size_t)(idn * W) * 256;

#pragma unroll
        for (int sx = 0; sx < 14; ++sx) {
            const float cx = ((float)sx + 0.5f) * wst + r1;
            const float fx = floorf(cx);
            int   il = (int)fx;
            int   ir = (int)ceilf(cx);
            const float lx = cx - fx;
            il = min(max(il, 0), W - 1);
            ir = min(max(ir, 0), W - 1);

            const float v00 = rowU[il * 256 + c];
            const float v01 = rowU[ir * 256 + c];
            const float v10 = rowD[il * 256 + c];
            const float v11 = rowD[ir * 256 + c];
            const float v = (v00 * (1.0f - lx) + v01 * lx) * wU
                          + (v10 * (1.0f - lx) + v11 * lx) * wD;
            m[sx >> 1] = fmaxf(m[sx >> 1], v);
        }
    }

    ushort2* outRow = pooledHL + (size_t)roi * PD + c;
#pragma unroll
    for (int pw = 0; pw < 7; ++pw)
        outRow[(ph * 7 + pw) * 256] = split_hl(m[pw]);
}

// ---------------------------------------------------------------------------
// W1 [12544][1024] fp32 -> W1T [1024 rows][25088] bf16 (transposed, hi/lo
// interleaved, GEMM1 k-permutation folded: dest pair p=cell*256+c sources
// row k=c*49+cell).
// ---------------------------------------------------------------------------
__global__ __launch_bounds__(256) void convert_w1_kernel(
    const float* __restrict__ W1, ushort2* __restrict__ W1T)
{
    __shared__ float tile[64][65];
    const int p0  = blockIdx.x * 64;
    const int n0  = blockIdx.y * 64;
    const int col = threadIdx.x & 63;
    const int r0  = threadIdx.x >> 6;
#pragma unroll
    for (int r = r0; r < 64; r += 4) {
        const int pp   = p0 + r;
        const int ksrc = (pp & 255) * 49 + (pp >> 8);
        tile[r][col] = W1[(size_t)ksrc * 1024 + n0 + col];
    }
    __syncthreads();
#pragma unroll
    for (int nr = r0; nr < 64; nr += 4)
        W1T[(size_t)(n0 + nr) * PD + p0 + col] = split_hl(tile[col][nr]);
}

// ---------------------------------------------------------------------------
// Merged: W2 -> W2T [1024][2048] (grid.y<16) and [Wloc|Wsc] -> WhT [512][2048]
// (grid.y>=16). Both transposed + hi/lo interleaved.
// ---------------------------------------------------------------------------
__global__ __launch_bounds__(256) void convert_w2h_kernel(
    const float* __restrict__ W2, const float* __restrict__ Wloc,
    const float* __restrict__ Wsc, ushort2* __restrict__ W2T,
    ushort2* __restrict__ WhT)
{
    __shared__ float tile[64][65];
    const int p0  = blockIdx.x * 64;
    const int col = threadIdx.x & 63;
    const int r0  = threadIdx.x >> 6;

    if (blockIdx.y < 16) {
        const int n0 = blockIdx.y * 64;
#pragma unroll
        for (int r = r0; r < 64; r += 4)
            tile[r][col] = W2[(size_t)(p0 + r) * 1024 + n0 + col];
        __syncthreads();
#pragma unroll
        for (int nr = r0; nr < 64; nr += 4)
            W2T[(size_t)(n0 + nr) * 1024 + p0 + col] = split_hl(tile[col][nr]);
    } else {
        const int n0 = (blockIdx.y - 16) * 64;
#pragma unroll
        for (int r = r0; r < 64; r += 4) {
            const int pp = p0 + r;
            const int n  = n0 + col;
            float v = 0.0f;
            if (n < NLOC)    v = Wloc[(size_t)pp * NLOC + n];
            else if (n < NH) v = Wsc[(size_t)pp * NSC + (n - NLOC)];
            tile[r][col] = v;
        }
        __syncthreads();
#pragma unroll
        for (int nr = r0; nr < 64; nr += 4)
            WhT[(size_t)(n0 + nr) * 1024 + p0 + col] = split_hl(tile[col][nr]);
    }
}

// ---------------------------------------------------------------------------
// bf16 MFMA GEMM, m97-style: 128x128 tile, BK=64, global_load_lds width 16,
// XOR-swizzled LDS chunks. A [Mpad][K2], B [Npad][K2] row-major bf16.
// partial[z] = A[:, z*kLen:(z+1)*kLen] @ B^T slice.
// ---------------------------------------------------------------------------
__global__ __launch_bounds__(256, 2) void gemm_bf16_kernel(
    const unsigned short* __restrict__ A,
    const unsigned short* __restrict__ B,
    float* __restrict__ partial,
    int K2, int N, int kLen)
{
    __shared__ __align__(16) unsigned short As[128 * 64];
    __shared__ __align__(16) unsigned short Bs[128 * 64];

    const int tid  = threadIdx.x;
    const int lane = tid & 63;
    const int wave = tid >> 6;
    const int m0 = blockIdx.y * 128;
    const int n0 = blockIdx.x * 128;
    const int kStart = blockIdx.z * kLen;

    const int rIn  = lane >> 3;
    const int cSrc = (lane & 7) ^ rIn;

    const int wm = wave >> 1, wn = wave & 1;
    const int mrow = lane & 15, quad = lane >> 4;

    floatx4 acc[4][4];
#pragma unroll
    for (int i = 0; i < 4; ++i)
#pragma unroll
        for (int j = 0; j < 4; ++j)
            acc[i][j] = (floatx4){0.f, 0.f, 0.f, 0.f};

    for (int k0 = kStart; k0 < kStart + kLen; k0 += 64) {
#pragma unroll
        for (int q = 0; q < 4; ++q) {
            const int rowBase = wave * 32 + q * 8;
            const unsigned short* ga =
                A + (size_t)(m0 + rowBase + rIn) * K2 + k0 + cSrc * 8;
            const unsigned short* gb =
                B + (size_t)(n0 + rowBase + rIn) * K2 + k0 + cSrc * 8;
            __builtin_amdgcn_global_load_lds(
                (const __attribute__((address_space(1))) void*)ga,
                (__attribute__((address_space(3))) void*)&As[rowBase * 64], 16, 0, 0);
            __builtin_amdgcn_global_load_lds(
                (const __attribute__((address_space(1))) void*)gb,
                (__attribute__((address_space(3))) void*)&Bs[rowBase * 64], 16, 0, 0);
        }
        __syncthreads();

#pragma unroll
        for (int ks = 0; ks < 2; ++ks) {
            bf16x8 aF[4], bF[4];
#pragma unroll
            for (int i = 0; i < 4; ++i) {
                const int ra = wm * 64 + i * 16 + mrow;
                const int ca = ((ks * 4 + quad) ^ (ra & 7)) * 8;
                aF[i] = *reinterpret_cast<const bf16x8*>(&As[ra * 64 + ca]);
                const int rb = wn * 64 + i * 16 + mrow;
                const int cb = ((ks * 4 + quad) ^ (rb & 7)) * 8;
                bF[i] = *reinterpret_cast<const bf16x8*>(&Bs[rb * 64 + cb]);
            }
#pragma unroll
            for (int i = 0; i < 4; ++i)
#pragma unroll
                for (int j = 0; j < 4; ++j)
                    acc[i][j] = __builtin_amdgcn_mfma_f32_16x16x32_bf16(
                        aF[i], bF[j], acc[i][j], 0, 0, 0);
        }
        __syncthreads();
    }

    float* p = partial + (size_t)blockIdx.z * (size_t)(gridDim.y * 128) * N;
#pragma unroll
    for (int i = 0; i < 4; ++i) {
        const int row = m0 + wm * 64 + i * 16 + quad * 4;
#pragma unroll
        for (int j = 0; j < 4; ++j) {
            const int col = n0 + wn * 64 + j * 16 + mrow;
#pragma unroll
            for (int r = 0; r < 4; ++r)
                p[(size_t)(row + r) * N + col] = acc[i][j][r];
        }
    }
}

// ---------------------------------------------------------------------------
// fc = relu(sum_z partial + bias) -> hi/lo bf16 interleaved. float4 path.
// ---------------------------------------------------------------------------
__global__ __launch_bounds__(256) void reduce_fc_kernel(
    const float* __restrict__ partial, const float* __restrict__ bias,
    ushort2* __restrict__ outHL, int nz)
{
    const int i4 = blockIdx.x * 256 + threadIdx.x;    // float4 idx < 256000
    const int off = i4 * 4;
    const int m = off >> 10, n = off & 1023;
    float4 acc = *reinterpret_cast<const float4*>(partial + off);
    for (int z = 1; z < nz; ++z) {
        const float4 v = *reinterpret_cast<const float4*>(
            partial + (size_t)z * 1024 * 1024 + off);
        acc.x += v.x; acc.y += v.y; acc.z += v.z; acc.w += v.w;
    }
    const float4 bv = *reinterpret_cast<const float4*>(bias + n);
    ushort2* o = outHL + (size_t)m * 1024 + n;
    o[0] = split_hl(fmaxf(acc.x + bv.x, 0.f));
    o[1] = split_hl(fmaxf(acc.y + bv.y, 0.f));
    o[2] = split_hl(fmaxf(acc.z + bv.z, 0.f));
    o[3] = split_hl(fmaxf(acc.w + bv.w, 0.f));
}

// heads: sum partials [z][1024][512], add bias, split-store to out0/out1
__global__ __launch_bounds__(256) void reduce_heads_kernel(
    const float* __restrict__ partial, const float* __restrict__ bloc,
    const float* __restrict__ bsc, float* __restrict__ out0,
    float* __restrict__ out1, int nz)
{
    const int m = blockIdx.x;   // 0..999
    for (int n = threadIdx.x; n < NH; n += 256) {
        float s = 0.f;
        for (int z = 0; z < nz; ++z)
            s += partial[(size_t)z * 1024 * 512 + (size_t)m * 512 + n];
        if (n < NLOC) out0[(size_t)m * NLOC + n] = s + bloc[n];
        else          out1[(size_t)m * NSC + (n - NLOC)] = s + bsc[n - NLOC];
    }
}

// ---------------------------------------------------------------------------
extern "C" void kernel_launch(void* const* d_in, const int* in_sizes, int n_in,
                              void* d_out, int out_size, void* d_ws, size_t ws_size,
                              hipStream_t stream)
{
    const float* f2   = (const float*)d_in[0];
    const float* f3   = (const float*)d_in[1];
    const float* f4   = (const float*)d_in[2];
    const float* f5   = (const float*)d_in[3];
    const float* rois = (const float*)d_in[4];
    const int*   img  = (const int*)d_in[5];
    const float* W1   = (const float*)d_in[6];
    const float* b1   = (const float*)d_in[7];
    const float* W2   = (const float*)d_in[8];
    const float* b2   = (const float*)d_in[9];
    const float* Wloc = (const float*)d_in[10];
    const float* bloc = (const float*)d_in[11];
    const float* Wsc  = (const float*)d_in[12];
    const float* bsc  = (const float*)d_in[13];
    float* out = (float*)d_out;

    float* ws = (float*)d_ws;
    float*   fT     = ws + OFF_FT;
    ushort2* pooled = (ushort2*)(ws + OFF_POOL);
    ushort2* w1t    = (ushort2*)(ws + OFF_W1T);     // aliases fT (dead then)
    float*   part   = ws + OFF_PART;                // aliases fT tail
    ushort2* w2t    = (ushort2*)(ws + OFF_W2T);
    ushort2* wht    = (ushort2*)(ws + OFF_WHT);
    ushort2* fc1    = (ushort2*)(ws + OFF_FC1);
    ushort2* fc2    = (ushort2*)(ws + OFF_FC2);

    // 1) feature transpose to [pix][256], all levels fused
    transpose_feat_kernel<<<dim3(1360, 4), 256, 0, stream>>>(f2, f3, f4, f5, fT);

    // 2) ROI pool, block per (roi, ph)
    roi_pool_kernel<<<dim3(NROIS, 7), 256, 0, stream>>>(fT, rois, img, pooled);

    // 3) weight conversions (W1T aliases fT region, dead after roi_pool)
    convert_w1_kernel<<<dim3(196, 16), 256, 0, stream>>>(W1, w1t);
    convert_w2h_kernel<<<dim3(16, 23), 256, 0, stream>>>(W2, Wloc, Wsc, w2t, wht);

    // 4) fc1 = relu(pooled @ W1 + b1): K2=25088, splitK=8 (512 blocks)
    gemm_bf16_kernel<<<dim3(8, 8, 8), 256, 0, stream>>>(
        (const unsigned short*)pooled, (const unsigned short*)w1t, part,
        K2_1, 1024, K2_1 / 8);
    reduce_fc_kernel<<<1024, 256, 0, stream>>>(part, b1, fc1, 8);

    // 5) fc2 = relu(fc1 @ W2 + b2): K2=2048, splitK=4 (256 blocks, 8 iters)
    gemm_bf16_kernel<<<dim3(8, 8, 4), 256, 0, stream>>>(
        (const unsigned short*)fc1, (const unsigned short*)w2t, part,
        K2_2, 1024, K2_2 / 4);
    reduce_fc_kernel<<<1024, 256, 0, stream>>>(part, b2, fc2, 4);

    // 6) heads: N=512 (cols 405..511 garbage, never stored), splitK=8
    gemm_bf16_kernel<<<dim3(4, 8, 8), 256, 0, stream>>>(
        (const unsigned short*)fc2, (const unsigned short*)wht, part,
        K2_2, 512, K2_2 / 8);
    reduce_heads_kernel<<<NROIS, 256, 0, stream>>>(
        part, bloc, bsc, out, out + (size_t)NROIS * NLOC, 8);
}

// Round 6
// 380.145 us; speedup vs baseline: 5.0307x; 1.0356x over previous
//
#include <hip/hip_runtime.h>
#include <hip/hip_bf16.h>
#include <cstdint>
#include <cstddef>

typedef __bf16 bf16x8 __attribute__((ext_vector_type(8)));
typedef float floatx4 __attribute__((ext_vector_type(4)));

#define NROIS 1000
#define PD    12544   // 256*49
#define K2_1  25088   // 2*PD  (hi/lo interleaved)
#define FC_N  1024
#define K2_2  2048    // 2*1024
#define NLOC  324
#define NSC   81
#define NH    405

// ---- workspace layout (float offsets) -------------------------------------
#define OFF_FT   0u          // fT: 22,282,240 floats (89.1 MB), dead after roi_pool
#define OFF_W1T  0u          // aliases fT: 1024*25088 bf16 = 12,845,056 floats
#define OFF_PART 12845056u   // 8*1024*1024 fp32 = 8,388,608 floats (in fT region)
#define OFF_T2   0u
#define OFF_T3   16777216u
#define OFF_T4   20971520u
#define OFF_T5   22020096u
#define OFF_POOL 22282240u   // pooled_hl: 1024*25088 bf16 = 12,845,056 floats
#define OFF_W2T  35127296u   // 1024*2048 bf16 = 1,048,576 floats
#define OFF_WHT  36175872u   // 512*2048 bf16  =   524,288 floats
#define OFF_FC1  36700160u   // 1024*2048 bf16 = 1,048,576 floats
#define OFF_FC2  37748736u   // end = 38,797,312 floats (155.2 MB)

// ---- bf16 hi/lo helpers ----------------------------------------------------
__device__ __forceinline__ unsigned short f2bf(float x) {
    unsigned int u = __float_as_uint(x);
    u = u + 0x7fffu + ((u >> 16) & 1u);          // RNE
    return (unsigned short)(u >> 16);
}
__device__ __forceinline__ float bf2f(unsigned short h) {
    return __uint_as_float(((unsigned int)h) << 16);
}
__device__ __forceinline__ ushort2 split_hl(float f) {
    const unsigned short hi = f2bf(f);
    const unsigned short lo = f2bf(f - bf2f(hi));
    return make_ushort2(hi, lo);
}

// ---------------------------------------------------------------------------
// Fused transpose of all 4 pyramid levels [256][P] -> [P][256] fp32.
// ---------------------------------------------------------------------------
__global__ __launch_bounds__(256) void transpose_feat_kernel(
    const float* __restrict__ f2, const float* __restrict__ f3,
    const float* __restrict__ f4, const float* __restrict__ f5,
    float* __restrict__ fT)
{
    __shared__ float tile[64][65];
    int bx = blockIdx.x;
    const float* src; float* dst; int P;
    if (bx < 1024)      {            src = f2; dst = fT + OFF_T2; P = 65536; }
    else if (bx < 1280) { bx -= 1024; src = f3; dst = fT + OFF_T3; P = 16384; }
    else if (bx < 1344) { bx -= 1280; src = f4; dst = fT + OFF_T4; P = 4096; }
    else                { bx -= 1344; src = f5; dst = fT + OFF_T5; P = 1024; }

    const int p0  = bx * 64;
    const int c0  = blockIdx.y * 64;
    const int col = threadIdx.x & 63;
    const int r0  = threadIdx.x >> 6;
#pragma unroll
    for (int r = r0; r < 64; r += 4)
        tile[r][col] = src[(size_t)(c0 + r) * P + p0 + col];
    __syncthreads();
#pragma unroll
    for (int r = r0; r < 64; r += 4)
        dst[(size_t)(p0 + r) * 256 + c0 + col] = tile[col][r];
}

// ---------------------------------------------------------------------------
// ROI align + 2x2 max: one block per (roi, ph); lane = channel.
// Output: interleaved hi/lo bf16 [roi][cell*256+c].
// ---------------------------------------------------------------------------
__global__ __launch_bounds__(256) void roi_pool_kernel(
    const float* __restrict__ fT, const float* __restrict__ rois,
    const int* __restrict__ img_size, ushort2* __restrict__ pooledHL)
{
    const int roi = blockIdx.x;        // 0..999
    const int ph  = blockIdx.y;        // 0..6
    const int c   = threadIdx.x;

    const float y1 = rois[roi * 4 + 0];
    const float x1 = rois[roi * 4 + 1];
    const float y2 = rois[roi * 4 + 2];
    const float x2 = rois[roi * 4 + 3];

    const float hh = y2 - y1 + 1.0f;
    const float ww = x2 - x1 + 1.0f;
    float lvlf = floorf(logf(sqrtf(hh * ww) / 224.0f) / 0.693147f + 4.0f);
    lvlf = fminf(fmaxf(lvlf, 2.0f), 5.0f);
    const int lvl = (int)lvlf;

    const float* f;
    int H;
    if (lvl == 2)      { f = fT + OFF_T2; H = 256; }
    else if (lvl == 3) { f = fT + OFF_T3; H = 128; }
    else if (lvl == 4) { f = fT + OFF_T4; H = 64;  }
    else               { f = fT + OFF_T5; H = 32;  }
    const int W = H;

    const float imh = (float)img_size[0] - 1.0f;
    const float imw = (float)img_size[1] - 1.0f;
    const float r0 = y1 * (float)(H - 1) / imh;
    const float r1 = x1 * (float)(W - 1) / imw;
    const float r2 = y2 * (float)(H - 1) / imh;
    const float r3 = x2 * (float)(W - 1) / imw;
    const float hs  = (r2 - r0) * (1.0f / 14.0f);
    const float wst = (r3 - r1) * (1.0f / 14.0f);

    float m[7];
#pragma unroll
    for (int i = 0; i < 7; ++i) m[i] = -INFINITY;

#pragma unroll
    for (int syy = 0; syy < 2; ++syy) {
        const float cy = ((float)(ph * 2 + syy) + 0.5f) * hs + r0;
        const float fy = floorf(cy);
        int   iu  = (int)fy;
        int   idn = (int)ceilf(cy);
        const float ly = cy - fy;
        iu  = min(max(iu, 0),  H - 1);
        idn = min(max(idn, 0), H - 1);
        const float wU = 1.0f - ly, wD = ly;
        const float* rowU = f + (size_t)(iu  * W) * 256;
        const float* rowD = f + (size_t)(idn * W) * 256;

#pragma unroll
        for (int sx = 0; sx < 14; ++sx) {
            const float cx = ((float)sx + 0.5f) * wst + r1;
            const float fx = floorf(cx);
            int   il = (int)fx;
            int   ir = (int)ceilf(cx);
            const float lx = cx - fx;
            il = min(max(il, 0), W - 1);
            ir = min(max(ir, 0), W - 1);

            const float v00 = rowU[il * 256 + c];
            const float v01 = rowU[ir * 256 + c];
            const float v10 = rowD[il * 256 + c];
            const float v11 = rowD[ir * 256 + c];
            const float v = (v00 * (1.0f - lx) + v01 * lx) * wU
                          + (v10 * (1.0f - lx) + v11 * lx) * wD;
            m[sx >> 1] = fmaxf(m[sx >> 1], v);
        }
    }

    ushort2* outRow = pooledHL + (size_t)roi * PD + c;
#pragma unroll
    for (int pw = 0; pw < 7; ++pw)
        outRow[(ph * 7 + pw) * 256] = split_hl(m[pw]);
}

// ---------------------------------------------------------------------------
// W1 [12544][1024] fp32 -> W1T [1024 rows][25088] bf16 (transposed, hi/lo
// interleaved, GEMM1 k-permutation folded).
// ---------------------------------------------------------------------------
__global__ __launch_bounds__(256) void convert_w1_kernel(
    const float* __restrict__ W1, ushort2* __restrict__ W1T)
{
    __shared__ float tile[64][65];
    const int p0  = blockIdx.x * 64;
    const int n0  = blockIdx.y * 64;
    const int col = threadIdx.x & 63;
    const int r0  = threadIdx.x >> 6;
#pragma unroll
    for (int r = r0; r < 64; r += 4) {
        const int pp   = p0 + r;
        const int ksrc = (pp & 255) * 49 + (pp >> 8);
        tile[r][col] = W1[(size_t)ksrc * 1024 + n0 + col];
    }
    __syncthreads();
#pragma unroll
    for (int nr = r0; nr < 64; nr += 4)
        W1T[(size_t)(n0 + nr) * PD + p0 + col] = split_hl(tile[col][nr]);
}

// ---------------------------------------------------------------------------
// Merged: W2 -> W2T [1024][2048] (grid.y<16) and [Wloc|Wsc] -> WhT [512][2048]
// ---------------------------------------------------------------------------
__global__ __launch_bounds__(256) void convert_w2h_kernel(
    const float* __restrict__ W2, const float* __restrict__ Wloc,
    const float* __restrict__ Wsc, ushort2* __restrict__ W2T,
    ushort2* __restrict__ WhT)
{
    __shared__ float tile[64][65];
    const int p0  = blockIdx.x * 64;
    const int col = threadIdx.x & 63;
    const int r0  = threadIdx.x >> 6;

    if (blockIdx.y < 16) {
        const int n0 = blockIdx.y * 64;
#pragma unroll
        for (int r = r0; r < 64; r += 4)
            tile[r][col] = W2[(size_t)(p0 + r) * 1024 + n0 + col];
        __syncthreads();
#pragma unroll
        for (int nr = r0; nr < 64; nr += 4)
            W2T[(size_t)(n0 + nr) * 1024 + p0 + col] = split_hl(tile[col][nr]);
    } else {
        const int n0 = (blockIdx.y - 16) * 64;
#pragma unroll
        for (int r = r0; r < 64; r += 4) {
            const int pp = p0 + r;
            const int n  = n0 + col;
            float v = 0.0f;
            if (n < NLOC)    v = Wloc[(size_t)pp * NLOC + n];
            else if (n < NH) v = Wsc[(size_t)pp * NSC + (n - NLOC)];
            tile[r][col] = v;
        }
        __syncthreads();
#pragma unroll
        for (int nr = r0; nr < 64; nr += 4)
            WhT[(size_t)(n0 + nr) * 1024 + p0 + col] = split_hl(tile[col][nr]);
    }
}

// ---------------------------------------------------------------------------
// bf16 MFMA GEMM v2: tile 64(M)x128(N), BK=64, global_load_lds width 16,
// XOR-swizzled LDS. grid = (splitK, N/128, M/64) so blockIdx.x (k-slice)
// maps to XCD (id%8 heuristic) -> per-XCD working set = its own A+B k-slice.
// 24 KB LDS + launch_bounds(256,4) -> 4 blocks/CU (16 waves) for latency
// hiding. A [Mpad][K2], B [Npad][K2] row-major bf16.
// partial[z][m][n], z-stride = (gridDim.z*64)*N.
// ---------------------------------------------------------------------------
__global__ __launch_bounds__(256, 4) void gemm_bf16_kernel(
    const unsigned short* __restrict__ A,
    const unsigned short* __restrict__ B,
    float* __restrict__ partial,
    int K2, int N, int kLen)
{
    __shared__ __align__(16) unsigned short As[64 * 64];    // 8 KB
    __shared__ __align__(16) unsigned short Bs[128 * 64];   // 16 KB

    const int tid  = threadIdx.x;
    const int lane = tid & 63;
    const int wave = tid >> 6;
    const int kStart = blockIdx.x * kLen;
    const int n0 = blockIdx.y * 128;
    const int m0 = blockIdx.z * 64;

    const int rIn  = lane >> 3;          // 0..7
    const int cSrc = (lane & 7) ^ rIn;   // XOR-swizzled source chunk

    const int mrow = lane & 15, quad = lane >> 4;

    floatx4 acc[8];
#pragma unroll
    for (int j = 0; j < 8; ++j)
        acc[j] = (floatx4){0.f, 0.f, 0.f, 0.f};

    for (int k0 = kStart; k0 < kStart + kLen; k0 += 64) {
        // stage A: wave w -> rows [w*16, w*16+16)
#pragma unroll
        for (int q = 0; q < 2; ++q) {
            const int rowBase = wave * 16 + q * 8;
            const unsigned short* ga =
                A + (size_t)(m0 + rowBase + rIn) * K2 + k0 + cSrc * 8;
            __builtin_amdgcn_global_load_lds(
                (const __attribute__((address_space(1))) void*)ga,
                (__attribute__((address_space(3))) void*)&As[rowBase * 64], 16, 0, 0);
        }
        // stage B: wave w -> rows [w*32, w*32+32)
#pragma unroll
        for (int q = 0; q < 4; ++q) {
            const int rowBase = wave * 32 + q * 8;
            const unsigned short* gb =
                B + (size_t)(n0 + rowBase + rIn) * K2 + k0 + cSrc * 8;
            __builtin_amdgcn_global_load_lds(
                (const __attribute__((address_space(1))) void*)gb,
                (__attribute__((address_space(3))) void*)&Bs[rowBase * 64], 16, 0, 0);
        }
        __syncthreads();

#pragma unroll
        for (int ks = 0; ks < 2; ++ks) {
            const int ra = wave * 16 + mrow;
            const int ca = ((ks * 4 + quad) ^ (ra & 7)) * 8;
            const bf16x8 aF = *reinterpret_cast<const bf16x8*>(&As[ra * 64 + ca]);
#pragma unroll
            for (int j = 0; j < 8; ++j) {
                const int rb = j * 16 + mrow;
                const int cb = ((ks * 4 + quad) ^ (rb & 7)) * 8;
                const bf16x8 bF = *reinterpret_cast<const bf16x8*>(&Bs[rb * 64 + cb]);
                acc[j] = __builtin_amdgcn_mfma_f32_16x16x32_bf16(aF, bF, acc[j], 0, 0, 0);
            }
        }
        __syncthreads();
    }

    // C/D layout: col = lane&15, row = quad*4 + reg
    float* p = partial + (size_t)blockIdx.x * (size_t)(gridDim.z * 64) * N;
    const int row = m0 + wave * 16 + quad * 4;
#pragma unroll
    for (int j = 0; j < 8; ++j) {
        const int col = n0 + j * 16 + mrow;
#pragma unroll
        for (int r = 0; r < 4; ++r)
            p[(size_t)(row + r) * N + col] = acc[j][r];
    }
}

// ---------------------------------------------------------------------------
// fc = relu(sum_z partial + bias) -> hi/lo bf16 interleaved. float4 path.
// ---------------------------------------------------------------------------
__global__ __launch_bounds__(256) void reduce_fc_kernel(
    const float* __restrict__ partial, const float* __restrict__ bias,
    ushort2* __restrict__ outHL, int nz)
{
    const int i4 = blockIdx.x * 256 + threadIdx.x;
    const int off = i4 * 4;
    const int m = off >> 10, n = off & 1023;
    float4 acc = *reinterpret_cast<const float4*>(partial + off);
    for (int z = 1; z < nz; ++z) {
        const float4 v = *reinterpret_cast<const float4*>(
            partial + (size_t)z * 1024 * 1024 + off);
        acc.x += v.x; acc.y += v.y; acc.z += v.z; acc.w += v.w;
    }
    const float4 bv = *reinterpret_cast<const float4*>(bias + n);
    ushort2* o = outHL + (size_t)m * 1024 + n;
    o[0] = split_hl(fmaxf(acc.x + bv.x, 0.f));
    o[1] = split_hl(fmaxf(acc.y + bv.y, 0.f));
    o[2] = split_hl(fmaxf(acc.z + bv.z, 0.f));
    o[3] = split_hl(fmaxf(acc.w + bv.w, 0.f));
}

// heads: sum partials [z][1024][512], add bias, split-store to out0/out1
__global__ __launch_bounds__(256) void reduce_heads_kernel(
    const float* __restrict__ partial, const float* __restrict__ bloc,
    const float* __restrict__ bsc, float* __restrict__ out0,
    float* __restrict__ out1, int nz)
{
    const int m = blockIdx.x;   // 0..999
    for (int n = threadIdx.x; n < NH; n += 256) {
        float s = 0.f;
        for (int z = 0; z < nz; ++z)
            s += partial[(size_t)z * 1024 * 512 + (size_t)m * 512 + n];
        if (n < NLOC) out0[(size_t)m * NLOC + n] = s + bloc[n];
        else          out1[(size_t)m * NSC + (n - NLOC)] = s + bsc[n - NLOC];
    }
}

// ---------------------------------------------------------------------------
extern "C" void kernel_launch(void* const* d_in, const int* in_sizes, int n_in,
                              void* d_out, int out_size, void* d_ws, size_t ws_size,
                              hipStream_t stream)
{
    const float* f2   = (const float*)d_in[0];
    const float* f3   = (const float*)d_in[1];
    const float* f4   = (const float*)d_in[2];
    const float* f5   = (const float*)d_in[3];
    const float* rois = (const float*)d_in[4];
    const int*   img  = (const int*)d_in[5];
    const float* W1   = (const float*)d_in[6];
    const float* b1   = (const float*)d_in[7];
    const float* W2   = (const float*)d_in[8];
    const float* b2   = (const float*)d_in[9];
    const float* Wloc = (const float*)d_in[10];
    const float* bloc = (const float*)d_in[11];
    const float* Wsc  = (const float*)d_in[12];
    const float* bsc  = (const float*)d_in[13];
    float* out = (float*)d_out;

    float* ws = (float*)d_ws;
    float*   fT     = ws + OFF_FT;
    ushort2* pooled = (ushort2*)(ws + OFF_POOL);
    ushort2* w1t    = (ushort2*)(ws + OFF_W1T);     // aliases fT (dead then)
    float*   part   = ws + OFF_PART;                // aliases fT tail
    ushort2* w2t    = (ushort2*)(ws + OFF_W2T);
    ushort2* wht    = (ushort2*)(ws + OFF_WHT);
    ushort2* fc1    = (ushort2*)(ws + OFF_FC1);
    ushort2* fc2    = (ushort2*)(ws + OFF_FC2);

    // 1) feature transpose to [pix][256], all levels fused
    transpose_feat_kernel<<<dim3(1360, 4), 256, 0, stream>>>(f2, f3, f4, f5, fT);

    // 2) ROI pool, block per (roi, ph)
    roi_pool_kernel<<<dim3(NROIS, 7), 256, 0, stream>>>(fT, rois, img, pooled);

    // 3) weight conversions (W1T aliases fT region, dead after roi_pool)
    convert_w1_kernel<<<dim3(196, 16), 256, 0, stream>>>(W1, w1t);
    convert_w2h_kernel<<<dim3(16, 23), 256, 0, stream>>>(W2, Wloc, Wsc, w2t, wht);

    // 4) fc1 = relu(pooled @ W1 + b1): grid (k=8, n=8, m=16) = 1024 blocks
    gemm_bf16_kernel<<<dim3(8, 8, 16), 256, 0, stream>>>(
        (const unsigned short*)pooled, (const unsigned short*)w1t, part,
        K2_1, 1024, K2_1 / 8);
    reduce_fc_kernel<<<1024, 256, 0, stream>>>(part, b1, fc1, 8);

    // 5) fc2 = relu(fc1 @ W2 + b2): grid (k=4, n=8, m=16) = 512 blocks
    gemm_bf16_kernel<<<dim3(4, 8, 16), 256, 0, stream>>>(
        (const unsigned short*)fc1, (const unsigned short*)w2t, part,
        K2_2, 1024, K2_2 / 4);
    reduce_fc_kernel<<<1024, 256, 0, stream>>>(part, b2, fc2, 4);

    // 6) heads: N=512, grid (k=8, n=4, m=16) = 512 blocks
    gemm_bf16_kernel<<<dim3(8, 4, 16), 256, 0, stream>>>(
        (const unsigned short*)fc2, (const unsigned short*)wht, part,
        K2_2, 512, K2_2 / 8);
    reduce_heads_kernel<<<NROIS, 256, 0, stream>>>(
        part, bloc, bsc, out, out + (size_t)NROIS * NLOC, 8);
}